// Round 14
// baseline (104.049 us; speedup 1.0000x reference)
//
#include <hip/hip_runtime.h>
#include <math.h>

#define DMODEL 512
#define NSEQ 2048
#define NHEAD 8
#define DK 64
#define DV 64
#define MFEAT 266
#define MPAD 288        // padded feature dim for bf16 MFMA (zero tail), mult of 32
#define NT 32           // number of chunks (chunk = 64)
#define LN_EPS 1e-6f
#define KERNEL_EPS 1e-4f
#define NORM_STAB 1e-6f
#define SCALE 0.21022410381342863f  // 512^-0.25

typedef __attribute__((ext_vector_type(8))) short short8;
typedef __attribute__((ext_vector_type(4))) short sv4;
typedef __attribute__((ext_vector_type(4))) float f32x4;

__device__ inline short f2bf(float f) {
    unsigned u = __builtin_bit_cast(unsigned, f);
    unsigned r = (u + 0x7fff + ((u >> 16) & 1)) >> 16;
    return (short)r;
}
__device__ inline float bf2f(short s) {
    unsigned u = ((unsigned)(unsigned short)s) << 16;
    return __builtin_bit_cast(float, u);
}

// ============ fused QKV GEMM + random-feature map ============
// grid (nt=32, h=8, z=3): same-A-rows blocks (all h) land on the same XCD -> A fetched once.
// z=0: LN(q)@Wq -> featQ -> qp. z=1: k@Wk -> h_k -> featK -> kp. z=2: v@Wv -> vh.
// rf fragments are read directly from global fp32 (L2-resident) during the proj MFMAs:
// no rfb LDS staging (kills the 8-way conflicts), LDS 38.1KB -> 4 blocks/CU.
__global__ __launch_bounds__(256) void qkvfeat_kernel(const float* __restrict__ qx,
                                                      const float* __restrict__ kx,
                                                      const float* __restrict__ vx,
                                                      const float* __restrict__ Wq,
                                                      const float* __restrict__ Wk,
                                                      const float* __restrict__ Wv,
                                                      const float* __restrict__ gamma,
                                                      const float* __restrict__ beta,
                                                      const float* __restrict__ rf,
                                                      short* __restrict__ vh,
                                                      short* __restrict__ qp,
                                                      short* __restrict__ kp) {
    __shared__ __align__(16) char smem[38144];
    auto As = (short(*)[40])smem;              // GEMM phase
    auto Bs = (short(*)[40])(smem + 5120);
    auto Xs = (short(*)[72])smem;              // feat input (overlays As/Bs after GEMM)
    short* kpl = (short*)smem;                 // 64x296 output staging (overlays Xs after xb read)
    float* hks = (float*)(smem + 37888);       // 64 floats

    int z = blockIdx.z;
    const float* A = (z == 0) ? qx : (z == 1) ? kx : vx;
    const float* B = (z == 0) ? Wq : (z == 1) ? Wk : Wv;
    float scale = (z == 2) ? 1.f : SCALE;
    int nt = blockIdx.x, h = blockIdx.y;
    int bm = nt * 64, bn = h * 64, n0 = nt * 64;
    int tid = threadIdx.x;
    int wid = tid >> 6, lane = tid & 63;
    f32x4 acc[4] = {f32x4{0,0,0,0}, f32x4{0,0,0,0}, f32x4{0,0,0,0}, f32x4{0,0,0,0}};
    int ar = tid >> 2, akq = tid & 3;
    int bkk = tid >> 3, bng = tid & 7;
    float lnm = 0.f, lnr = 0.f;
    if (z == 0) {
        // per-quad LN stats for row bm+ar (4 threads per row)
        const float* xr = qx + (size_t)(bm + ar) * DMODEL + akq * 128;
        float s = 0.f, ss = 0.f;
#pragma unroll 4
        for (int i = 0; i < 128; i += 4) {
            f32x4 vv = *(const f32x4*)(xr + i);
            s += vv[0] + vv[1] + vv[2] + vv[3];
            ss += vv[0]*vv[0] + vv[1]*vv[1] + vv[2]*vv[2] + vv[3]*vv[3];
        }
        s += __shfl_xor(s, 1); s += __shfl_xor(s, 2);
        ss += __shfl_xor(ss, 1); ss += __shfl_xor(ss, 2);
        float m = s / (float)DMODEL;
        float var = ss / (float)DMODEL - m * m;
        lnm = m;
        lnr = rsqrtf(var + LN_EPS);
    }
    for (int k0 = 0; k0 < DMODEL; k0 += 32) {
        {
            const float* src = A + (size_t)(bm + ar) * DMODEL + k0 + akq * 8;
            f32x4 v0 = *(const f32x4*)src;
            f32x4 v1 = *(const f32x4*)(src + 4);
            short8 sv;
            if (z == 0) {
                f32x4 g0 = *(const f32x4*)&gamma[k0 + akq * 8];
                f32x4 g1 = *(const f32x4*)&gamma[k0 + akq * 8 + 4];
                f32x4 bb0 = *(const f32x4*)&beta[k0 + akq * 8];
                f32x4 bb1 = *(const f32x4*)&beta[k0 + akq * 8 + 4];
                for (int j = 0; j < 4; ++j) {
                    sv[j] = f2bf((v0[j] - lnm) * lnr * g0[j] + bb0[j]);
                    sv[4 + j] = f2bf((v1[j] - lnm) * lnr * g1[j] + bb1[j]);
                }
            } else {
                for (int j = 0; j < 4; ++j) { sv[j] = f2bf(v0[j]); sv[4 + j] = f2bf(v1[j]); }
            }
            *(short8*)&As[ar][akq * 8] = sv;
        }
        {
            const float* src = B + (size_t)(k0 + bkk) * DMODEL + bn + bng * 8;
            f32x4 v0 = *(const f32x4*)src;
            f32x4 v1 = *(const f32x4*)(src + 4);
            for (int j = 0; j < 4; ++j) {
                Bs[bng * 8 + j][bkk] = f2bf(v0[j] * scale);
                Bs[bng * 8 + 4 + j][bkk] = f2bf(v1[j] * scale);
            }
        }
        __syncthreads();
        int row = wid * 16 + (lane & 15);
        int koff = (lane >> 4) * 8;
        short8 a = *(const short8*)&As[row][koff];
        for (int nf = 0; nf < 4; ++nf) {
            int col = nf * 16 + (lane & 15);
            short8 b = *(const short8*)&Bs[col][koff];
            acc[nf] = __builtin_amdgcn_mfma_f32_16x16x32_bf16(a, b, acc[nf], 0, 0, 0);
        }
        __syncthreads();
    }
    if (z == 2) {
        // V path: write vh and exit
        for (int nf = 0; nf < 4; ++nf) {
            int col = bn + nf * 16 + (lane & 15);
            for (int j = 0; j < 4; ++j) {
                int row = bm + wid * 16 + (lane >> 4) * 4 + j;
                vh[(size_t)row * DMODEL + col] = f2bf(acc[nf][j]);
            }
        }
        return;
    }
    // ---- feat phase: C tile -> Xs (bf16); overlays dead As/Bs (post final GEMM barrier) ----
    for (int nf = 0; nf < 4; ++nf) {
        int col = nf * 16 + (lane & 15);
        for (int j = 0; j < 4; ++j) {
            int row = wid * 16 + (lane >> 4) * 4 + j;
            Xs[row][col] = f2bf(acc[nf][j]);
        }
    }
    if (z == 1) {
        // local h_k per row from fp32 accumulators
        for (int j = 0; j < 4; ++j) {
            float ss = 0.f;
            for (int nf = 0; nf < 4; ++nf) ss += acc[nf][j] * acc[nf][j];
            for (int o = 1; o < 16; o <<= 1) ss += __shfl_xor(ss, o);
            if ((lane & 15) == 0) hks[wid * 16 + (lane >> 4) * 4 + j] = -0.5f * ss;
        }
    }
    __syncthreads();

    int w = wid, l = lane;
    int fr = l & 15, fq = (l >> 4) * 8;
    short8 xb0 = *(const short8*)&Xs[w * 16 + fr][fq];
    short8 xb1 = *(const short8*)&Xs[w * 16 + fr][32 + fq];
    int n_loc = w * 16 + fr;
    float hval = (z == 1) ? hks[n_loc] : 0.f;
    __syncthreads();  // xb/hks reads done; Xs region becomes kpl

    // proj MFMA: C[m][n] = sum_d rf_bf16[m][d] * Xs[n][d]; A fragments from GLOBAL fp32
    f32x4 facc[18];
#pragma unroll
    for (int tr = 0; tr < 18; ++tr) facc[tr] = f32x4{0, 0, 0, 0};
#pragma unroll 2
    for (int tr = 0; tr < 18; ++tr) {
        int row = tr * 16 + fr;
        short8 a0, a1;
        if (row < MFEAT) {
            const float* rp = rf + (size_t)row * DK;
            f32x4 v0 = *(const f32x4*)(rp + fq);
            f32x4 v1 = *(const f32x4*)(rp + fq + 4);
            f32x4 v2 = *(const f32x4*)(rp + 32 + fq);
            f32x4 v3 = *(const f32x4*)(rp + 32 + fq + 4);
            for (int j = 0; j < 4; ++j) {
                a0[j] = f2bf(v0[j]); a0[4 + j] = f2bf(v1[j]);
                a1[j] = f2bf(v2[j]); a1[4 + j] = f2bf(v3[j]);
            }
        } else {
            for (int j = 0; j < 8; ++j) { a0[j] = 0; a1[j] = 0; }
        }
        facc[tr] = __builtin_amdgcn_mfma_f32_16x16x32_bf16(a0, xb0, facc[tr], 0, 0, 0);
        facc[tr] = __builtin_amdgcn_mfma_f32_16x16x32_bf16(a1, xb1, facc[tr], 0, 0, 0);
    }

    short (*kpl2)[296] = (short(*)[296])kpl;
    const float cnorm = 0.06131393394849658f;  // 266^-0.5
#pragma unroll
    for (int tr = 0; tr < 18; ++tr) {
        sv4 o;
        for (int j = 0; j < 4; ++j) {
            int m = tr * 16 + (l >> 4) * 4 + j;
            float val = (m < MFEAT) ? cnorm * (expf(facc[tr][j] + hval) + KERNEL_EPS) : 0.f;
            o[j] = f2bf(val);
        }
        *(sv4*)&kpl2[n_loc][tr * 16 + (l >> 4) * 4] = o;
    }
    __syncthreads();
    // coalesced copy kpl rows -> HBM
    short* outp = (z == 0) ? qp : kp;
    for (int lp = 0; lp < 9; ++lp) {
        int c = tid + lp * 256;      // 64 rows * 36 chunks
        int nn = c / 36, c8 = c % 36;
        short8 v = *(const short8*)&kpl2[nn][c8 * 8];
        *(short8*)&outp[((size_t)h * NSEQ + n0 + nn) * MPAD + c8 * 8] = v;
    }
}

// ---------------- phase A (MFMA): per-chunk sums -> bf16 KVc[(h,t,dv)][m], fp32 Ks[(h,t)][m] ----------------
__global__ __launch_bounds__(256) void chunksum_kernel(const short* __restrict__ kp,
                                                       const short* __restrict__ vh,
                                                       short* __restrict__ KVc,
                                                       float* __restrict__ Ks) {
    int t = blockIdx.x, h = blockIdx.y;
    __shared__ short kpT[288 * 72];   // [m][i-swizzled], stride 72 shorts (144B); 41.5KB
    __shared__ short Vt[64][72];      // [dv][i]
    int tid = threadIdx.x;
    int w = tid >> 6, l = tid & 63;
    int fr = l & 15, fq8 = (l >> 4) * 8;
    const short* kpb = kp + ((size_t)h * NSEQ + (size_t)t * 64) * MPAD;

    // stage kp^T: read rows coalesced, scatter to swizzled columns
    for (int lp = 0; lp < 9; ++lp) {
        int c = tid + lp * 256;       // 2304 = 64 i * 36 m-chunks
        int i = c / 36, c8 = c % 36;
        short8 v = *(const short8*)&kpb[(size_t)i * MPAD + c8 * 8];
        int i8 = i >> 3, i7 = i & 7;
        for (int jj = 0; jj < 8; ++jj) {
            int m = c8 * 8 + jj;
            int ig = i8 ^ ((m >> 3) & 7);
            kpT[m * 72 + ig * 8 + i7] = v[jj];
        }
    }
    // stage V^T
    for (int lp = 0; lp < 2; ++lp) {
        int c = tid + lp * 256;       // 512 = 64 i * 8 d-chunks
        int i = c & 63, d8 = (c >> 6) * 8;
        short8 v = *(const short8*)&vh[(size_t)(t * 64 + i) * DMODEL + h * DV + d8];
        for (int jj = 0; jj < 8; ++jj) Vt[d8 + jj][i] = v[jj];
    }
    __syncthreads();

    // D[m][dv] = sum_i kp^T[m][i] * V[i][dv]; wave w owns m-tiles {w, w+4, ...}
    f32x4 acc[5][4];
#pragma unroll
    for (int tt = 0; tt < 5; ++tt)
        for (int nf = 0; nf < 4; ++nf) acc[tt][nf] = f32x4{0, 0, 0, 0};
#pragma unroll
    for (int tt = 0; tt < 5; ++tt) {
        int tr = w + tt * 4;
        if (tr < 18) {
            int row = tr * 16 + fr;
            int swz = (row >> 3) & 7;
            short8 a0 = *(const short8*)&kpT[row * 72 + (((fq8 >> 3)) ^ swz) * 8];
            short8 a1 = *(const short8*)&kpT[row * 72 + ((4 + (fq8 >> 3)) ^ swz) * 8];
            for (int nf = 0; nf < 4; ++nf) {
                short8 b0 = *(const short8*)&Vt[nf * 16 + fr][fq8];
                short8 b1 = *(const short8*)&Vt[nf * 16 + fr][32 + fq8];
                acc[tt][nf] = __builtin_amdgcn_mfma_f32_16x16x32_bf16(a0, b0, acc[tt][nf], 0, 0, 0);
                acc[tt][nf] = __builtin_amdgcn_mfma_f32_16x16x32_bf16(a1, b1, acc[tt][nf], 0, 0, 0);
            }
        }
    }
    // Ks[m] = sum_i kp^T[m][i]
    for (int m = tid; m < MPAD; m += 256) {
        int swz = (m >> 3) & 7;
        float s = 0.f;
        for (int i8 = 0; i8 < 8; ++i8) {
            int ig = i8 ^ swz;
            for (int j = 0; j < 8; ++j) s += bf2f(kpT[m * 72 + ig * 8 + j]);
        }
        Ks[((size_t)h * NT + t) * MPAD + m] = s;
    }
    __syncthreads();  // kpT reads done; overlay kvT
    short* kvT = kpT; // [64 dv][296 m]
#pragma unroll
    for (int tt = 0; tt < 5; ++tt) {
        int tr = w + tt * 4;
        if (tr < 18) {
            for (int nf = 0; nf < 4; ++nf) {
                int dv = nf * 16 + fr;
                for (int j = 0; j < 4; ++j) {
                    int m = tr * 16 + (l >> 4) * 4 + j;
                    kvT[dv * 296 + m] = f2bf(acc[tt][nf][j]);
                }
            }
        }
    }
    __syncthreads();
    // coalesced KVc store
    for (int lp = 0; lp < 9; ++lp) {
        int c = tid + lp * 256;       // 2304 = 64 dv * 36
        int dv = c / 36, c8 = c % 36;
        short8 v = *(const short8*)&kvT[dv * 296 + c8 * 8];
        *(short8*)&KVc[(((size_t)h * NT + t) * DV + dv) * MPAD + c8 * 8] = v;
    }
}

// ---------------- fused exclusive chunk-scans, batched loads ----------------
__global__ __launch_bounds__(256) void scan_kernel(const short* __restrict__ KVc,
                                                   short* __restrict__ KVbT,
                                                   float* __restrict__ Ks,
                                                   float* __restrict__ Ktot) {
    int idx = blockIdx.x * 256 + threadIdx.x;
    const int NKV = NHEAD * DV * MPAD;       // 147456
    if (idx < NKV) {
        int h = idx / (DV * MPAD);
        int rem = idx % (DV * MPAD);
        size_t base = (size_t)h * NT * DV * MPAD + rem;
        short vals[NT];
#pragma unroll
        for (int t = 0; t < NT; ++t) vals[t] = KVc[base + (size_t)t * DV * MPAD];
        float run = 0.f;
#pragma unroll
        for (int t = 0; t < NT; ++t) {
            KVbT[base + (size_t)t * DV * MPAD] = f2bf(run);
            run += bf2f(vals[t]);
        }
    } else {
        int j = idx - NKV;
        if (j < NHEAD * MPAD) {
            int h = j / MPAD, m = j % MPAD;
            size_t base = (size_t)h * NT * MPAD + m;
            float vals[NT];
#pragma unroll
            for (int t = 0; t < NT; ++t) vals[t] = Ks[base + (size_t)t * MPAD];
            float run = 0.f;
#pragma unroll
            for (int t = 0; t < NT; ++t) {
                Ks[base + (size_t)t * MPAD] = run;
                run += vals[t];
            }
            Ktot[(size_t)h * MPAD + m] = run;
        }
    }
}

// ---------------- phase C: MFMA intra+inter+denominators; bf16 out ----------------
__global__ __launch_bounds__(256) void phasec_kernel(const short* __restrict__ qp,
                                                     const short* __restrict__ kp,
                                                     const short* __restrict__ vh,
                                                     const short* __restrict__ KVbT,
                                                     const float* __restrict__ Ks,
                                                     const float* __restrict__ Ktot,
                                                     short* __restrict__ attn) {
    int t = blockIdx.x, h = blockIdx.y;
    __shared__ short Buf[64][296];   // Kp (QK^T phase) then St (inter phase)
    __shared__ short Vt[64][72];     // [dv][i]
    __shared__ short Am[64][72];     // masked A, bf16
    __shared__ float Ksp[MPAD], Ktp[MPAD];
    __shared__ float fscale_s[64];
    int tid = threadIdx.x;
    int w = tid >> 6, l = tid & 63;
    int fr = l & 15, fq = (l >> 4) * 8;
    const short* qpb = qp + ((size_t)h * NSEQ + (size_t)t * 64) * MPAD;
    const short* kpb = kp + ((size_t)h * NSEQ + (size_t)t * 64) * MPAD;
    const short* stb = KVbT + ((size_t)h * NT + t) * DV * MPAD;

    short8 qf[9];
#pragma unroll
    for (int ks = 0; ks < 9; ++ks)
        qf[ks] = *(const short8*)&qpb[(size_t)(w * 16 + fr) * MPAD + ks * 32 + fq];

    int srow = tid >> 2, sc4 = tid & 3;
#pragma unroll
    for (int lp = 0; lp < 9; ++lp) {
        int c = sc4 + lp * 4;
        *(short8*)&Buf[srow][c * 8] = *(const short8*)&kpb[(size_t)srow * MPAD + c * 8];
    }
    // stage Vt via row reads + LDS transpose
    for (int lp = 0; lp < 2; ++lp) {
        int c = tid + lp * 256;
        int i = c & 63, d8 = (c >> 6) * 8;
        short8 v = *(const short8*)&vh[(size_t)(t * 64 + i) * DMODEL + h * DV + d8];
        for (int jj = 0; jj < 8; ++jj) Vt[d8 + jj][i] = v[jj];
    }
    for (int idx = tid; idx < MPAD; idx += 256) {
        Ksp[idx] = Ks[((size_t)h * NT + t) * MPAD + idx];
        Ktp[idx] = Ktot[(size_t)h * MPAD + idx];
    }
    // async-issue S^T loads; latency hides under QK^T MFMAs
    short8 stg[9];
#pragma unroll
    for (int lp = 0; lp < 9; ++lp) {
        int c = sc4 + lp * 4;
        stg[lp] = *(const short8*)&stb[(size_t)srow * MPAD + c * 8];
    }
    __syncthreads();

    f32x4 accA[4] = {f32x4{0,0,0,0}, f32x4{0,0,0,0}, f32x4{0,0,0,0}, f32x4{0,0,0,0}};
    f32x4 accO[4] = {f32x4{0,0,0,0}, f32x4{0,0,0,0}, f32x4{0,0,0,0}, f32x4{0,0,0,0}};
#pragma unroll 3
    for (int ks = 0; ks < 9; ++ks) {
        int ko = ks * 32 + fq;
        for (int nf = 0; nf < 4; ++nf) {
            short8 bk = *(const short8*)&Buf[nf * 16 + fr][ko];
            accA[nf] = __builtin_amdgcn_mfma_f32_16x16x32_bf16(qf[ks], bk, accA[nf], 0, 0, 0);
        }
    }
    __syncthreads();
#pragma unroll
    for (int lp = 0; lp < 9; ++lp) {
        int c = sc4 + lp * 4;
        *(short8*)&Buf[srow][c * 8] = stg[lp];
    }
    for (int nf = 0; nf < 4; ++nf) {
        int col = nf * 16 + fr;
        for (int j = 0; j < 4; ++j) {
            int row = w * 16 + (l >> 4) * 4 + j;
            Am[row][col] = (col <= row) ? f2bf(accA[nf][j]) : (short)0;
        }
    }
    __syncthreads();
#pragma unroll 3
    for (int ks = 0; ks < 9; ++ks) {
        int ko = ks * 32 + fq;
        for (int nf = 0; nf < 4; ++nf) {
            short8 bs = *(const short8*)&Buf[nf * 16 + fr][ko];
            accO[nf] = __builtin_amdgcn_mfma_f32_16x16x32_bf16(qf[ks], bs, accO[nf], 0, 0, 0);
        }
    }
#pragma unroll
    for (int ks = 0; ks < 2; ++ks) {
        int ko = ks * 32 + fq;
        short8 a = *(const short8*)&Am[w * 16 + fr][ko];
        for (int nf = 0; nf < 4; ++nf) {
            short8 b = *(const short8*)&Vt[nf * 16 + fr][ko];
            accO[nf] = __builtin_amdgcn_mfma_f32_16x16x32_bf16(a, b, accO[nf], 0, 0, 0);
        }
    }
    int di = tid >> 2, dp = tid & 3;
    float dc = 0.f, df = 0.f;
    {
        const short* amrow = &Am[di][dp * 16];
        short8 s0 = *(const short8*)amrow;
        short8 s1 = *(const short8*)(amrow + 8);
        for (int j2 = 0; j2 < 8; ++j2) dc += bf2f(s0[j2]) + bf2f(s1[j2]);
    }
#pragma unroll
    for (int c8 = 0; c8 < 9; ++c8) {
        int m = dp * 72 + c8 * 8;
        short8 qv = *(const short8*)&qpb[(size_t)di * MPAD + m];
        for (int j2 = 0; j2 < 8; ++j2) {
            float qq = bf2f(qv[j2]);
            dc += qq * Ksp[m + j2];
            df += qq * Ktp[m + j2];
        }
    }
    dc += __shfl_xor(dc, 1); dc += __shfl_xor(dc, 2);
    df += __shfl_xor(df, 1); df += __shfl_xor(df, 2);
    if (dp == 0) {
        float dst = df;
        if (fabsf(dst) <= NORM_STAB) dst += 2.f * NORM_STAB;
        fscale_s[di] = (1.f / dc) / dst;
    }
    __syncthreads();
    for (int nf = 0; nf < 4; ++nf) {
        int col = nf * 16 + fr;
        for (int j = 0; j < 4; ++j) {
            int row = w * 16 + (l >> 4) * 4 + j;
            attn[((size_t)t * 64 + row) * DMODEL + h * DV + col] =
                f2bf(accO[nf][j] * fscale_s[row]);
        }
    }
}

// ---------------- final GEMM with bias + residual (A is bf16) ----------------
__global__ __launch_bounds__(256) void fgemm_kernel(const short* __restrict__ A,
                                                    const float* __restrict__ B,
                                                    float* __restrict__ C,
                                                    const float* __restrict__ bias,
                                                    const float* __restrict__ residual) {
    __shared__ short As[64][40];
    __shared__ short Bs[64][40];
    int bm = blockIdx.y * 64, bn = blockIdx.x * 64;
    int tid = threadIdx.x;
    int wid = tid >> 6, lane = tid & 63;
    f32x4 acc[4] = {f32x4{0,0,0,0}, f32x4{0,0,0,0}, f32x4{0,0,0,0}, f32x4{0,0,0,0}};
    int ar = tid >> 2, akq = tid & 3;
    int bkk = tid >> 3, bng = tid & 7;
    for (int k0 = 0; k0 < DMODEL; k0 += 32) {
        {
            const short* src = A + (size_t)(bm + ar) * DMODEL + k0 + akq * 8;
            *(short8*)&As[ar][akq * 8] = *(const short8*)src;
        }
        {
            const float* src = B + (size_t)(k0 + bkk) * DMODEL + bn + bng * 8;
            f32x4 v0 = *(const f32x4*)src;
            f32x4 v1 = *(const f32x4*)(src + 4);
            for (int j = 0; j < 4; ++j) {
                Bs[bng * 8 + j][bkk] = f2bf(v0[j]);
                Bs[bng * 8 + 4 + j][bkk] = f2bf(v1[j]);
            }
        }
        __syncthreads();
        int row = wid * 16 + (lane & 15);
        int koff = (lane >> 4) * 8;
        short8 a = *(const short8*)&As[row][koff];
        for (int nf = 0; nf < 4; ++nf) {
            int col = nf * 16 + (lane & 15);
            short8 b = *(const short8*)&Bs[col][koff];
            acc[nf] = __builtin_amdgcn_mfma_f32_16x16x32_bf16(a, b, acc[nf], 0, 0, 0);
        }
        __syncthreads();
    }
    for (int nf = 0; nf < 4; ++nf) {
        int col = bn + nf * 16 + (lane & 15);
        for (int j = 0; j < 4; ++j) {
            int row = bm + wid * 16 + (lane >> 4) * 4 + j;
            C[(size_t)row * DMODEL + col] =
                acc[nf][j] + bias[col] + residual[(size_t)row * DMODEL + col];
        }
    }
}

extern "C" void kernel_launch(void* const* d_in, const int* in_sizes, int n_in,
                              void* d_out, int out_size, void* d_ws, size_t ws_size,
                              hipStream_t stream) {
    const float* q = (const float*)d_in[0];
    const float* k = (const float*)d_in[1];
    const float* v = (const float*)d_in[2];
    const float* Wq = (const float*)d_in[3];
    const float* Wk = (const float*)d_in[4];
    const float* Wv = (const float*)d_in[5];
    const float* Wfc = (const float*)d_in[6];
    const float* bfc = (const float*)d_in[7];
    const float* gamma = (const float*)d_in[8];
    const float* beta = (const float*)d_in[9];
    const float* rf = (const float*)d_in[10];
    float* out = (float*)d_out;

    float* ws = (float*)d_ws;
    short* attn = (short*)ws;                              // bf16 2048*512
    short* vhb = attn + (size_t)NSEQ * DMODEL;             // bf16 2048*512
    short* qp = vhb + (size_t)NSEQ * DMODEL;               // bf16 8*2048*288
    short* kp = qp + (size_t)NHEAD * NSEQ * MPAD;
    short* KVc = kp + (size_t)NHEAD * NSEQ * MPAD;         // bf16 8*32*64*288
    short* KVbT = KVc + (size_t)NHEAD * NT * DV * MPAD;
    float* Ks = (float*)(KVbT + (size_t)NHEAD * NT * DV * MPAD);   // fp32 8*32*288
    float* Ktot = Ks + (size_t)NHEAD * NT * MPAD;          // 8*288

    dim3 gq(NT, NHEAD, 3);
    qkvfeat_kernel<<<gq, 256, 0, stream>>>(q, k, v, Wq, Wk, Wv, gamma, beta, rf,
                                           vhb, qp, kp);
    dim3 ga(NT, NHEAD);
    chunksum_kernel<<<ga, 256, 0, stream>>>(kp, vhb, KVc, Ks);
    int scan_threads = NHEAD * DV * MPAD + NHEAD * MPAD;
    scan_kernel<<<(scan_threads + 255) / 256, 256, 0, stream>>>(KVc, KVbT, Ks, Ktot);
    dim3 gc(NT, NHEAD);
    phasec_kernel<<<gc, 256, 0, stream>>>(qp, kp, vhb, KVbT, Ks, Ktot, attn);
    dim3 g(DMODEL / 64, NSEQ / 64);
    fgemm_kernel<<<g, 256, 0, stream>>>(attn, Wfc, out, bfc, q);
}

// Round 15
// 87.038 us; speedup vs baseline: 1.1955x; 1.1955x over previous
//
#include <hip/hip_runtime.h>
#include <math.h>

#define DMODEL 512
#define NSEQ 2048
#define NHEAD 8
#define DK 64
#define DV 64
#define MFEAT 266
#define MPAD 288        // padded feature dim for bf16 MFMA (zero tail), mult of 32
#define NT 32           // number of chunks (chunk = 64)
#define LN_EPS 1e-6f
#define KERNEL_EPS 1e-4f
#define NORM_STAB 1e-6f
#define SCALE 0.21022410381342863f  // 512^-0.25

typedef __attribute__((ext_vector_type(8))) short short8;
typedef __attribute__((ext_vector_type(4))) short sv4;
typedef __attribute__((ext_vector_type(4))) float f32x4;

__device__ inline short f2bf(float f) {
    unsigned u = __builtin_bit_cast(unsigned, f);
    unsigned r = (u + 0x7fff + ((u >> 16) & 1)) >> 16;
    return (short)r;
}
__device__ inline float bf2f(short s) {
    unsigned u = ((unsigned)(unsigned short)s) << 16;
    return __builtin_bit_cast(float, u);
}

// ============ fused QKV GEMM + random-feature map ============
// grid (nt=32, h=8, z=3): same-A-rows blocks on same XCD (FETCH 65->51MB verified R14).
// proj loop: NO facc array (rule #20: runtime-indexed ext_vector -> scratch; R14's 91MB
// write regression). Each tr: 2 MFMAs into a local f32x4, exp, store — fully unrolled.
__global__ __launch_bounds__(256) void qkvfeat_kernel(const float* __restrict__ qx,
                                                      const float* __restrict__ kx,
                                                      const float* __restrict__ vx,
                                                      const float* __restrict__ Wq,
                                                      const float* __restrict__ Wk,
                                                      const float* __restrict__ Wv,
                                                      const float* __restrict__ gamma,
                                                      const float* __restrict__ beta,
                                                      const float* __restrict__ rf,
                                                      short* __restrict__ vh,
                                                      short* __restrict__ qp,
                                                      short* __restrict__ kp) {
    __shared__ __align__(16) char smem[38656];
    auto As = (short(*)[40])smem;              // GEMM phase
    auto Bs = (short(*)[40])(smem + 5120);
    auto Xs = (short(*)[72])smem;              // feat input (overlays As/Bs after GEMM)
    short* kpl = (short*)smem;                 // 64x300 output staging (overlays Xs after xb read)
    float* hks = (float*)(smem + 38400);       // 64 floats

    int z = blockIdx.z;
    const float* A = (z == 0) ? qx : (z == 1) ? kx : vx;
    const float* B = (z == 0) ? Wq : (z == 1) ? Wk : Wv;
    float scale = (z == 2) ? 1.f : SCALE;
    int nt = blockIdx.x, h = blockIdx.y;
    int bm = nt * 64, bn = h * 64, n0 = nt * 64;
    int tid = threadIdx.x;
    int wid = tid >> 6, lane = tid & 63;
    f32x4 acc[4] = {f32x4{0,0,0,0}, f32x4{0,0,0,0}, f32x4{0,0,0,0}, f32x4{0,0,0,0}};
    int ar = tid >> 2, akq = tid & 3;
    int bkk = tid >> 3, bng = tid & 7;
    float lnm = 0.f, lnr = 0.f;
    if (z == 0) {
        // per-quad LN stats for row bm+ar (4 threads per row)
        const float* xr = qx + (size_t)(bm + ar) * DMODEL + akq * 128;
        float s = 0.f, ss = 0.f;
#pragma unroll 4
        for (int i = 0; i < 128; i += 4) {
            f32x4 vv = *(const f32x4*)(xr + i);
            s += vv[0] + vv[1] + vv[2] + vv[3];
            ss += vv[0]*vv[0] + vv[1]*vv[1] + vv[2]*vv[2] + vv[3]*vv[3];
        }
        s += __shfl_xor(s, 1); s += __shfl_xor(s, 2);
        ss += __shfl_xor(ss, 1); ss += __shfl_xor(ss, 2);
        float m = s / (float)DMODEL;
        float var = ss / (float)DMODEL - m * m;
        lnm = m;
        lnr = rsqrtf(var + LN_EPS);
    }
    for (int k0 = 0; k0 < DMODEL; k0 += 32) {
        {
            const float* src = A + (size_t)(bm + ar) * DMODEL + k0 + akq * 8;
            f32x4 v0 = *(const f32x4*)src;
            f32x4 v1 = *(const f32x4*)(src + 4);
            short8 sv;
            if (z == 0) {
                f32x4 g0 = *(const f32x4*)&gamma[k0 + akq * 8];
                f32x4 g1 = *(const f32x4*)&gamma[k0 + akq * 8 + 4];
                f32x4 bb0 = *(const f32x4*)&beta[k0 + akq * 8];
                f32x4 bb1 = *(const f32x4*)&beta[k0 + akq * 8 + 4];
                for (int j = 0; j < 4; ++j) {
                    sv[j] = f2bf((v0[j] - lnm) * lnr * g0[j] + bb0[j]);
                    sv[4 + j] = f2bf((v1[j] - lnm) * lnr * g1[j] + bb1[j]);
                }
            } else {
                for (int j = 0; j < 4; ++j) { sv[j] = f2bf(v0[j]); sv[4 + j] = f2bf(v1[j]); }
            }
            *(short8*)&As[ar][akq * 8] = sv;
        }
        {
            const float* src = B + (size_t)(k0 + bkk) * DMODEL + bn + bng * 8;
            f32x4 v0 = *(const f32x4*)src;
            f32x4 v1 = *(const f32x4*)(src + 4);
            for (int j = 0; j < 4; ++j) {
                Bs[bng * 8 + j][bkk] = f2bf(v0[j] * scale);
                Bs[bng * 8 + 4 + j][bkk] = f2bf(v1[j] * scale);
            }
        }
        __syncthreads();
        int row = wid * 16 + (lane & 15);
        int koff = (lane >> 4) * 8;
        short8 a = *(const short8*)&As[row][koff];
        for (int nf = 0; nf < 4; ++nf) {
            int col = nf * 16 + (lane & 15);
            short8 b = *(const short8*)&Bs[col][koff];
            acc[nf] = __builtin_amdgcn_mfma_f32_16x16x32_bf16(a, b, acc[nf], 0, 0, 0);
        }
        __syncthreads();
    }
    if (z == 2) {
        // V path: write vh and exit
        for (int nf = 0; nf < 4; ++nf) {
            int col = bn + nf * 16 + (lane & 15);
            for (int j = 0; j < 4; ++j) {
                int row = bm + wid * 16 + (lane >> 4) * 4 + j;
                vh[(size_t)row * DMODEL + col] = f2bf(acc[nf][j]);
            }
        }
        return;
    }
    // ---- feat phase: C tile -> Xs (bf16); overlays dead As/Bs (post final GEMM barrier) ----
    for (int nf = 0; nf < 4; ++nf) {
        int col = nf * 16 + (lane & 15);
        for (int j = 0; j < 4; ++j) {
            int row = wid * 16 + (lane >> 4) * 4 + j;
            Xs[row][col] = f2bf(acc[nf][j]);
        }
    }
    if (z == 1) {
        // local h_k per row from fp32 accumulators
        for (int j = 0; j < 4; ++j) {
            float ss = 0.f;
            for (int nf = 0; nf < 4; ++nf) ss += acc[nf][j] * acc[nf][j];
            for (int o = 1; o < 16; o <<= 1) ss += __shfl_xor(ss, o);
            if ((lane & 15) == 0) hks[wid * 16 + (lane >> 4) * 4 + j] = -0.5f * ss;
        }
    }
    __syncthreads();

    int w = wid, l = lane;
    int fr = l & 15, fq = (l >> 4) * 8;
    short8 xb0 = *(const short8*)&Xs[w * 16 + fr][fq];
    short8 xb1 = *(const short8*)&Xs[w * 16 + fr][32 + fq];
    int n_loc = w * 16 + fr;
    float hval = (z == 1) ? hks[n_loc] : 0.f;
    __syncthreads();  // xb/hks reads done; Xs region becomes kpl

    // proj MFMA per m-tile: rf from GLOBAL fp32, accumulate locally, exp, store.
    short (*kpl2)[300] = (short(*)[300])kpl;
    const float cnorm = 0.06131393394849658f;  // 266^-0.5
#pragma unroll
    for (int tr = 0; tr < 18; ++tr) {
        int row = tr * 16 + fr;
        short8 a0, a1;
        if (row < MFEAT) {
            const float* rp = rf + (size_t)row * DK;
            f32x4 v0 = *(const f32x4*)(rp + fq);
            f32x4 v1 = *(const f32x4*)(rp + fq + 4);
            f32x4 v2 = *(const f32x4*)(rp + 32 + fq);
            f32x4 v3 = *(const f32x4*)(rp + 32 + fq + 4);
            for (int j = 0; j < 4; ++j) {
                a0[j] = f2bf(v0[j]); a0[4 + j] = f2bf(v1[j]);
                a1[j] = f2bf(v2[j]); a1[4 + j] = f2bf(v3[j]);
            }
        } else {
            for (int j = 0; j < 8; ++j) { a0[j] = 0; a1[j] = 0; }
        }
        f32x4 facc = {0.f, 0.f, 0.f, 0.f};
        facc = __builtin_amdgcn_mfma_f32_16x16x32_bf16(a0, xb0, facc, 0, 0, 0);
        facc = __builtin_amdgcn_mfma_f32_16x16x32_bf16(a1, xb1, facc, 0, 0, 0);
        sv4 o;
        for (int j = 0; j < 4; ++j) {
            int m = tr * 16 + (l >> 4) * 4 + j;
            float val = (m < MFEAT) ? cnorm * (expf(facc[j] + hval) + KERNEL_EPS) : 0.f;
            o[j] = f2bf(val);
        }
        *(sv4*)&kpl2[n_loc][tr * 16 + (l >> 4) * 4] = o;
    }
    __syncthreads();
    // coalesced copy kpl rows -> HBM
    short* outp = (z == 0) ? qp : kp;
    for (int lp = 0; lp < 9; ++lp) {
        int c = tid + lp * 256;      // 64 rows * 36 chunks
        int nn = c / 36, c8 = c % 36;
        short8 v = *(const short8*)&kpl2[nn][c8 * 8];
        *(short8*)&outp[((size_t)h * NSEQ + n0 + nn) * MPAD + c8 * 8] = v;
    }
}

// ---------------- phase A (MFMA): per-chunk sums -> bf16 KVc[(h,t,dv)][m], fp32 Ks[(h,t)][m] ----------------
__global__ __launch_bounds__(256) void chunksum_kernel(const short* __restrict__ kp,
                                                       const short* __restrict__ vh,
                                                       short* __restrict__ KVc,
                                                       float* __restrict__ Ks) {
    int t = blockIdx.x, h = blockIdx.y;
    __shared__ short kpT[288 * 72];   // [m][i-swizzled], stride 72 shorts (144B); 41.5KB
    __shared__ short Vt[64][72];      // [dv][i]
    int tid = threadIdx.x;
    int w = tid >> 6, l = tid & 63;
    int fr = l & 15, fq8 = (l >> 4) * 8;
    const short* kpb = kp + ((size_t)h * NSEQ + (size_t)t * 64) * MPAD;

    // stage kp^T: read rows coalesced, scatter to swizzled columns
    for (int lp = 0; lp < 9; ++lp) {
        int c = tid + lp * 256;       // 2304 = 64 i * 36 m-chunks
        int i = c / 36, c8 = c % 36;
        short8 v = *(const short8*)&kpb[(size_t)i * MPAD + c8 * 8];
        int i8 = i >> 3, i7 = i & 7;
        for (int jj = 0; jj < 8; ++jj) {
            int m = c8 * 8 + jj;
            int ig = i8 ^ ((m >> 3) & 7);
            kpT[m * 72 + ig * 8 + i7] = v[jj];
        }
    }
    // stage V^T
    for (int lp = 0; lp < 2; ++lp) {
        int c = tid + lp * 256;       // 512 = 64 i * 8 d-chunks
        int i = c & 63, d8 = (c >> 6) * 8;
        short8 v = *(const short8*)&vh[(size_t)(t * 64 + i) * DMODEL + h * DV + d8];
        for (int jj = 0; jj < 8; ++jj) Vt[d8 + jj][i] = v[jj];
    }
    __syncthreads();

    // D[m][dv] = sum_i kp^T[m][i] * V[i][dv]; wave w owns m-tiles {w, w+4, ...}
    f32x4 acc[5][4];
#pragma unroll
    for (int tt = 0; tt < 5; ++tt)
        for (int nf = 0; nf < 4; ++nf) acc[tt][nf] = f32x4{0, 0, 0, 0};
#pragma unroll
    for (int tt = 0; tt < 5; ++tt) {
        int tr = w + tt * 4;
        if (tr < 18) {
            int row = tr * 16 + fr;
            int swz = (row >> 3) & 7;
            short8 a0 = *(const short8*)&kpT[row * 72 + (((fq8 >> 3)) ^ swz) * 8];
            short8 a1 = *(const short8*)&kpT[row * 72 + ((4 + (fq8 >> 3)) ^ swz) * 8];
            for (int nf = 0; nf < 4; ++nf) {
                short8 b0 = *(const short8*)&Vt[nf * 16 + fr][fq8];
                short8 b1 = *(const short8*)&Vt[nf * 16 + fr][32 + fq8];
                acc[tt][nf] = __builtin_amdgcn_mfma_f32_16x16x32_bf16(a0, b0, acc[tt][nf], 0, 0, 0);
                acc[tt][nf] = __builtin_amdgcn_mfma_f32_16x16x32_bf16(a1, b1, acc[tt][nf], 0, 0, 0);
            }
        }
    }
    // Ks[m] = sum_i kp^T[m][i]
    for (int m = tid; m < MPAD; m += 256) {
        int swz = (m >> 3) & 7;
        float s = 0.f;
        for (int i8 = 0; i8 < 8; ++i8) {
            int ig = i8 ^ swz;
            for (int j = 0; j < 8; ++j) s += bf2f(kpT[m * 72 + ig * 8 + j]);
        }
        Ks[((size_t)h * NT + t) * MPAD + m] = s;
    }
    __syncthreads();  // kpT reads done; overlay kvT
    short* kvT = kpT; // [64 dv][296 m]
#pragma unroll
    for (int tt = 0; tt < 5; ++tt) {
        int tr = w + tt * 4;
        if (tr < 18) {
            for (int nf = 0; nf < 4; ++nf) {
                int dv = nf * 16 + fr;
                for (int j = 0; j < 4; ++j) {
                    int m = tr * 16 + (l >> 4) * 4 + j;
                    kvT[dv * 296 + m] = f2bf(acc[tt][nf][j]);
                }
            }
        }
    }
    __syncthreads();
    // coalesced KVc store
    for (int lp = 0; lp < 9; ++lp) {
        int c = tid + lp * 256;       // 2304 = 64 dv * 36
        int dv = c / 36, c8 = c % 36;
        short8 v = *(const short8*)&kvT[dv * 296 + c8 * 8];
        *(short8*)&KVc[(((size_t)h * NT + t) * DV + dv) * MPAD + c8 * 8] = v;
    }
}

// ---------------- fused exclusive chunk-scans, batched loads ----------------
__global__ __launch_bounds__(256) void scan_kernel(const short* __restrict__ KVc,
                                                   short* __restrict__ KVbT,
                                                   float* __restrict__ Ks,
                                                   float* __restrict__ Ktot) {
    int idx = blockIdx.x * 256 + threadIdx.x;
    const int NKV = NHEAD * DV * MPAD;       // 147456
    if (idx < NKV) {
        int h = idx / (DV * MPAD);
        int rem = idx % (DV * MPAD);
        size_t base = (size_t)h * NT * DV * MPAD + rem;
        short vals[NT];
#pragma unroll
        for (int t = 0; t < NT; ++t) vals[t] = KVc[base + (size_t)t * DV * MPAD];
        float run = 0.f;
#pragma unroll
        for (int t = 0; t < NT; ++t) {
            KVbT[base + (size_t)t * DV * MPAD] = f2bf(run);
            run += bf2f(vals[t]);
        }
    } else {
        int j = idx - NKV;
        if (j < NHEAD * MPAD) {
            int h = j / MPAD, m = j % MPAD;
            size_t base = (size_t)h * NT * MPAD + m;
            float vals[NT];
#pragma unroll
            for (int t = 0; t < NT; ++t) vals[t] = Ks[base + (size_t)t * MPAD];
            float run = 0.f;
#pragma unroll
            for (int t = 0; t < NT; ++t) {
                Ks[base + (size_t)t * MPAD] = run;
                run += vals[t];
            }
            Ktot[(size_t)h * MPAD + m] = run;
        }
    }
}

// ---------------- phase C: MFMA intra+inter+denominators; bf16 out ----------------
__global__ __launch_bounds__(256) void phasec_kernel(const short* __restrict__ qp,
                                                     const short* __restrict__ kp,
                                                     const short* __restrict__ vh,
                                                     const short* __restrict__ KVbT,
                                                     const float* __restrict__ Ks,
                                                     const float* __restrict__ Ktot,
                                                     short* __restrict__ attn) {
    int t = blockIdx.x, h = blockIdx.y;
    __shared__ short Buf[64][296];   // Kp (QK^T phase) then St (inter phase)
    __shared__ short Vt[64][72];     // [dv][i]
    __shared__ short Am[64][72];     // masked A, bf16
    __shared__ float Ksp[MPAD], Ktp[MPAD];
    __shared__ float fscale_s[64];
    int tid = threadIdx.x;
    int w = tid >> 6, l = tid & 63;
    int fr = l & 15, fq = (l >> 4) * 8;
    const short* qpb = qp + ((size_t)h * NSEQ + (size_t)t * 64) * MPAD;
    const short* kpb = kp + ((size_t)h * NSEQ + (size_t)t * 64) * MPAD;
    const short* stb = KVbT + ((size_t)h * NT + t) * DV * MPAD;

    short8 qf[9];
#pragma unroll
    for (int ks = 0; ks < 9; ++ks)
        qf[ks] = *(const short8*)&qpb[(size_t)(w * 16 + fr) * MPAD + ks * 32 + fq];

    int srow = tid >> 2, sc4 = tid & 3;
#pragma unroll
    for (int lp = 0; lp < 9; ++lp) {
        int c = sc4 + lp * 4;
        *(short8*)&Buf[srow][c * 8] = *(const short8*)&kpb[(size_t)srow * MPAD + c * 8];
    }
    // stage Vt via row reads + LDS transpose
    for (int lp = 0; lp < 2; ++lp) {
        int c = tid + lp * 256;
        int i = c & 63, d8 = (c >> 6) * 8;
        short8 v = *(const short8*)&vh[(size_t)(t * 64 + i) * DMODEL + h * DV + d8];
        for (int jj = 0; jj < 8; ++jj) Vt[d8 + jj][i] = v[jj];
    }
    for (int idx = tid; idx < MPAD; idx += 256) {
        Ksp[idx] = Ks[((size_t)h * NT + t) * MPAD + idx];
        Ktp[idx] = Ktot[(size_t)h * MPAD + idx];
    }
    // async-issue S^T loads; latency hides under QK^T MFMAs
    short8 stg[9];
#pragma unroll
    for (int lp = 0; lp < 9; ++lp) {
        int c = sc4 + lp * 4;
        stg[lp] = *(const short8*)&stb[(size_t)srow * MPAD + c * 8];
    }
    __syncthreads();

    f32x4 accA[4] = {f32x4{0,0,0,0}, f32x4{0,0,0,0}, f32x4{0,0,0,0}, f32x4{0,0,0,0}};
    f32x4 accO[4] = {f32x4{0,0,0,0}, f32x4{0,0,0,0}, f32x4{0,0,0,0}, f32x4{0,0,0,0}};
#pragma unroll 3
    for (int ks = 0; ks < 9; ++ks) {
        int ko = ks * 32 + fq;
        for (int nf = 0; nf < 4; ++nf) {
            short8 bk = *(const short8*)&Buf[nf * 16 + fr][ko];
            accA[nf] = __builtin_amdgcn_mfma_f32_16x16x32_bf16(qf[ks], bk, accA[nf], 0, 0, 0);
        }
    }
    __syncthreads();
#pragma unroll
    for (int lp = 0; lp < 9; ++lp) {
        int c = sc4 + lp * 4;
        *(short8*)&Buf[srow][c * 8] = stg[lp];
    }
    for (int nf = 0; nf < 4; ++nf) {
        int col = nf * 16 + fr;
        for (int j = 0; j < 4; ++j) {
            int row = w * 16 + (l >> 4) * 4 + j;
            Am[row][col] = (col <= row) ? f2bf(accA[nf][j]) : (short)0;
        }
    }
    __syncthreads();
#pragma unroll 3
    for (int ks = 0; ks < 9; ++ks) {
        int ko = ks * 32 + fq;
        for (int nf = 0; nf < 4; ++nf) {
            short8 bs = *(const short8*)&Buf[nf * 16 + fr][ko];
            accO[nf] = __builtin_amdgcn_mfma_f32_16x16x32_bf16(qf[ks], bs, accO[nf], 0, 0, 0);
        }
    }
#pragma unroll
    for (int ks = 0; ks < 2; ++ks) {
        int ko = ks * 32 + fq;
        short8 a = *(const short8*)&Am[w * 16 + fr][ko];
        for (int nf = 0; nf < 4; ++nf) {
            short8 b = *(const short8*)&Vt[nf * 16 + fr][ko];
            accO[nf] = __builtin_amdgcn_mfma_f32_16x16x32_bf16(a, b, accO[nf], 0, 0, 0);
        }
    }
    int di = tid >> 2, dp = tid & 3;
    float dc = 0.f, df = 0.f;
    {
        const short* amrow = &Am[di][dp * 16];
        short8 s0 = *(const short8*)amrow;
        short8 s1 = *(const short8*)(amrow + 8);
        for (int j2 = 0; j2 < 8; ++j2) dc += bf2f(s0[j2]) + bf2f(s1[j2]);
    }
#pragma unroll
    for (int c8 = 0; c8 < 9; ++c8) {
        int m = dp * 72 + c8 * 8;
        short8 qv = *(const short8*)&qpb[(size_t)di * MPAD + m];
        for (int j2 = 0; j2 < 8; ++j2) {
            float qq = bf2f(qv[j2]);
            dc += qq * Ksp[m + j2];
            df += qq * Ktp[m + j2];
        }
    }
    dc += __shfl_xor(dc, 1); dc += __shfl_xor(dc, 2);
    df += __shfl_xor(df, 1); df += __shfl_xor(df, 2);
    if (dp == 0) {
        float dst = df;
        if (fabsf(dst) <= NORM_STAB) dst += 2.f * NORM_STAB;
        fscale_s[di] = (1.f / dc) / dst;
    }
    __syncthreads();
    for (int nf = 0; nf < 4; ++nf) {
        int col = nf * 16 + fr;
        for (int j = 0; j < 4; ++j) {
            int row = w * 16 + (l >> 4) * 4 + j;
            attn[((size_t)t * 64 + row) * DMODEL + h * DV + col] =
                f2bf(accO[nf][j] * fscale_s[row]);
        }
    }
}

// ---------------- final GEMM with bias + residual (A is bf16) ----------------
__global__ __launch_bounds__(256) void fgemm_kernel(const short* __restrict__ A,
                                                    const float* __restrict__ B,
                                                    float* __restrict__ C,
                                                    const float* __restrict__ bias,
                                                    const float* __restrict__ residual) {
    __shared__ short As[64][40];
    __shared__ short Bs[64][40];
    int bm = blockIdx.y * 64, bn = blockIdx.x * 64;
    int tid = threadIdx.x;
    int wid = tid >> 6, lane = tid & 63;
    f32x4 acc[4] = {f32x4{0,0,0,0}, f32x4{0,0,0,0}, f32x4{0,0,0,0}, f32x4{0,0,0,0}};
    int ar = tid >> 2, akq = tid & 3;
    int bkk = tid >> 3, bng = tid & 7;
    for (int k0 = 0; k0 < DMODEL; k0 += 32) {
        {
            const short* src = A + (size_t)(bm + ar) * DMODEL + k0 + akq * 8;
            *(short8*)&As[ar][akq * 8] = *(const short8*)src;
        }
        {
            const float* src = B + (size_t)(k0 + bkk) * DMODEL + bn + bng * 8;
            f32x4 v0 = *(const f32x4*)src;
            f32x4 v1 = *(const f32x4*)(src + 4);
            for (int j = 0; j < 4; ++j) {
                Bs[bng * 8 + j][bkk] = f2bf(v0[j]);
                Bs[bng * 8 + 4 + j][bkk] = f2bf(v1[j]);
            }
        }
        __syncthreads();
        int row = wid * 16 + (lane & 15);
        int koff = (lane >> 4) * 8;
        short8 a = *(const short8*)&As[row][koff];
        for (int nf = 0; nf < 4; ++nf) {
            int col = nf * 16 + (lane & 15);
            short8 b = *(const short8*)&Bs[col][koff];
            acc[nf] = __builtin_amdgcn_mfma_f32_16x16x32_bf16(a, b, acc[nf], 0, 0, 0);
        }
        __syncthreads();
    }
    for (int nf = 0; nf < 4; ++nf) {
        int col = bn + nf * 16 + (lane & 15);
        for (int j = 0; j < 4; ++j) {
            int row = bm + wid * 16 + (lane >> 4) * 4 + j;
            C[(size_t)row * DMODEL + col] =
                acc[nf][j] + bias[col] + residual[(size_t)row * DMODEL + col];
        }
    }
}

extern "C" void kernel_launch(void* const* d_in, const int* in_sizes, int n_in,
                              void* d_out, int out_size, void* d_ws, size_t ws_size,
                              hipStream_t stream) {
    const float* q = (const float*)d_in[0];
    const float* k = (const float*)d_in[1];
    const float* v = (const float*)d_in[2];
    const float* Wq = (const float*)d_in[3];
    const float* Wk = (const float*)d_in[4];
    const float* Wv = (const float*)d_in[5];
    const float* Wfc = (const float*)d_in[6];
    const float* bfc = (const float*)d_in[7];
    const float* gamma = (const float*)d_in[8];
    const float* beta = (const float*)d_in[9];
    const float* rf = (const float*)d_in[10];
    float* out = (float*)d_out;

    float* ws = (float*)d_ws;
    short* attn = (short*)ws;                              // bf16 2048*512
    short* vhb = attn + (size_t)NSEQ * DMODEL;             // bf16 2048*512
    short* qp = vhb + (size_t)NSEQ * DMODEL;               // bf16 8*2048*288
    short* kp = qp + (size_t)NHEAD * NSEQ * MPAD;
    short* KVc = kp + (size_t)NHEAD * NSEQ * MPAD;         // bf16 8*32*64*288
    short* KVbT = KVc + (size_t)NHEAD * NT * DV * MPAD;
    float* Ks = (float*)(KVbT + (size_t)NHEAD * NT * DV * MPAD);   // fp32 8*32*288
    float* Ktot = Ks + (size_t)NHEAD * NT * MPAD;          // 8*288

    dim3 gq(NT, NHEAD, 3);
    qkvfeat_kernel<<<gq, 256, 0, stream>>>(q, k, v, Wq, Wk, Wv, gamma, beta, rf,
                                           vhb, qp, kp);
    dim3 ga(NT, NHEAD);
    chunksum_kernel<<<ga, 256, 0, stream>>>(kp, vhb, KVc, Ks);
    int scan_threads = NHEAD * DV * MPAD + NHEAD * MPAD;
    scan_kernel<<<(scan_threads + 255) / 256, 256, 0, stream>>>(KVc, KVbT, Ks, Ktot);
    dim3 gc(NT, NHEAD);
    phasec_kernel<<<gc, 256, 0, stream>>>(qp, kp, vhb, KVbT, Ks, Ktot, attn);
    dim3 g(DMODEL / 64, NSEQ / 64);
    fgemm_kernel<<<g, 256, 0, stream>>>(attn, Wfc, out, bfc, q);
}

// Round 16
// 86.962 us; speedup vs baseline: 1.1965x; 1.0009x over previous
//
#include <hip/hip_runtime.h>
#include <hip/hip_bf16.h>
#include <math.h>

#define DMODEL 512
#define NSEQ 2048
#define NHEAD 8
#define DK 64
#define DV 64
#define MFEAT 266
#define MPAD 288        // padded feature dim for bf16 MFMA (zero tail), mult of 32
#define NT 32           // number of chunks (chunk = 64)
#define LN_EPS 1e-6f
#define KERNEL_EPS 1e-4f
#define NORM_STAB 1e-6f
#define SCALE 0.21022410381342863f  // 512^-0.25

typedef __attribute__((ext_vector_type(8))) short short8;
typedef __attribute__((ext_vector_type(4))) short sv4;
typedef __attribute__((ext_vector_type(4))) float f32x4;

// Compiler-native bf16 RNE cast (fuses to v_cvt_pk_bf16_f32; m240: don't hand-roll)
__device__ inline short f2bf(float f) {
    return (short)__bfloat16_as_ushort(__float2bfloat16(f));
}
__device__ inline float bf2f(short s) {
    unsigned u = ((unsigned)(unsigned short)s) << 16;
    return __builtin_bit_cast(float, u);
}

// ============ fused QKV GEMM + random-feature map ============
// grid (nt=32, h=8, z=3): same-A-rows blocks on same XCD (FETCH 65->19MB verified R15).
// VALU diet (R15 lesson): kernel was conversion/exp instruction-bound at VALUBusy 19% —
// f2bf now compiler cast, expf -> __expf.
__global__ __launch_bounds__(256) void qkvfeat_kernel(const float* __restrict__ qx,
                                                      const float* __restrict__ kx,
                                                      const float* __restrict__ vx,
                                                      const float* __restrict__ Wq,
                                                      const float* __restrict__ Wk,
                                                      const float* __restrict__ Wv,
                                                      const float* __restrict__ gamma,
                                                      const float* __restrict__ beta,
                                                      const float* __restrict__ rf,
                                                      short* __restrict__ vh,
                                                      short* __restrict__ qp,
                                                      short* __restrict__ kp) {
    __shared__ __align__(16) char smem[38656];
    auto As = (short(*)[40])smem;              // GEMM phase
    auto Bs = (short(*)[40])(smem + 5120);
    auto Xs = (short(*)[72])smem;              // feat input (overlays As/Bs after GEMM)
    short* kpl = (short*)smem;                 // 64x300 output staging (overlays Xs after xb read)
    float* hks = (float*)(smem + 38400);       // 64 floats

    int z = blockIdx.z;
    const float* A = (z == 0) ? qx : (z == 1) ? kx : vx;
    const float* B = (z == 0) ? Wq : (z == 1) ? Wk : Wv;
    float scale = (z == 2) ? 1.f : SCALE;
    int nt = blockIdx.x, h = blockIdx.y;
    int bm = nt * 64, bn = h * 64, n0 = nt * 64;
    int tid = threadIdx.x;
    int wid = tid >> 6, lane = tid & 63;
    f32x4 acc[4] = {f32x4{0,0,0,0}, f32x4{0,0,0,0}, f32x4{0,0,0,0}, f32x4{0,0,0,0}};
    int ar = tid >> 2, akq = tid & 3;
    int bkk = tid >> 3, bng = tid & 7;
    float lnm = 0.f, lnr = 0.f;
    if (z == 0) {
        // per-quad LN stats for row bm+ar (4 threads per row)
        const float* xr = qx + (size_t)(bm + ar) * DMODEL + akq * 128;
        float s = 0.f, ss = 0.f;
#pragma unroll 4
        for (int i = 0; i < 128; i += 4) {
            f32x4 vv = *(const f32x4*)(xr + i);
            s += vv[0] + vv[1] + vv[2] + vv[3];
            ss += vv[0]*vv[0] + vv[1]*vv[1] + vv[2]*vv[2] + vv[3]*vv[3];
        }
        s += __shfl_xor(s, 1); s += __shfl_xor(s, 2);
        ss += __shfl_xor(ss, 1); ss += __shfl_xor(ss, 2);
        float m = s / (float)DMODEL;
        float var = ss / (float)DMODEL - m * m;
        lnm = m;
        lnr = rsqrtf(var + LN_EPS);
    }
    for (int k0 = 0; k0 < DMODEL; k0 += 32) {
        {
            const float* src = A + (size_t)(bm + ar) * DMODEL + k0 + akq * 8;
            f32x4 v0 = *(const f32x4*)src;
            f32x4 v1 = *(const f32x4*)(src + 4);
            short8 sv;
            if (z == 0) {
                f32x4 g0 = *(const f32x4*)&gamma[k0 + akq * 8];
                f32x4 g1 = *(const f32x4*)&gamma[k0 + akq * 8 + 4];
                f32x4 bb0 = *(const f32x4*)&beta[k0 + akq * 8];
                f32x4 bb1 = *(const f32x4*)&beta[k0 + akq * 8 + 4];
                for (int j = 0; j < 4; ++j) {
                    sv[j] = f2bf((v0[j] - lnm) * lnr * g0[j] + bb0[j]);
                    sv[4 + j] = f2bf((v1[j] - lnm) * lnr * g1[j] + bb1[j]);
                }
            } else {
                for (int j = 0; j < 4; ++j) { sv[j] = f2bf(v0[j]); sv[4 + j] = f2bf(v1[j]); }
            }
            *(short8*)&As[ar][akq * 8] = sv;
        }
        {
            const float* src = B + (size_t)(k0 + bkk) * DMODEL + bn + bng * 8;
            f32x4 v0 = *(const f32x4*)src;
            f32x4 v1 = *(const f32x4*)(src + 4);
            for (int j = 0; j < 4; ++j) {
                Bs[bng * 8 + j][bkk] = f2bf(v0[j] * scale);
                Bs[bng * 8 + 4 + j][bkk] = f2bf(v1[j] * scale);
            }
        }
        __syncthreads();
        int row = wid * 16 + (lane & 15);
        int koff = (lane >> 4) * 8;
        short8 a = *(const short8*)&As[row][koff];
        for (int nf = 0; nf < 4; ++nf) {
            int col = nf * 16 + (lane & 15);
            short8 b = *(const short8*)&Bs[col][koff];
            acc[nf] = __builtin_amdgcn_mfma_f32_16x16x32_bf16(a, b, acc[nf], 0, 0, 0);
        }
        __syncthreads();
    }
    if (z == 2) {
        // V path: write vh and exit
        for (int nf = 0; nf < 4; ++nf) {
            int col = bn + nf * 16 + (lane & 15);
            for (int j = 0; j < 4; ++j) {
                int row = bm + wid * 16 + (lane >> 4) * 4 + j;
                vh[(size_t)row * DMODEL + col] = f2bf(acc[nf][j]);
            }
        }
        return;
    }
    // ---- feat phase: C tile -> Xs (bf16); overlays dead As/Bs ----
    for (int nf = 0; nf < 4; ++nf) {
        int col = nf * 16 + (lane & 15);
        for (int j = 0; j < 4; ++j) {
            int row = wid * 16 + (lane >> 4) * 4 + j;
            Xs[row][col] = f2bf(acc[nf][j]);
        }
    }
    if (z == 1) {
        // local h_k per row from fp32 accumulators
        for (int j = 0; j < 4; ++j) {
            float ss = 0.f;
            for (int nf = 0; nf < 4; ++nf) ss += acc[nf][j] * acc[nf][j];
            for (int o = 1; o < 16; o <<= 1) ss += __shfl_xor(ss, o);
            if ((lane & 15) == 0) hks[wid * 16 + (lane >> 4) * 4 + j] = -0.5f * ss;
        }
    }
    __syncthreads();

    int w = wid, l = lane;
    int fr = l & 15, fq = (l >> 4) * 8;
    short8 xb0 = *(const short8*)&Xs[w * 16 + fr][fq];
    short8 xb1 = *(const short8*)&Xs[w * 16 + fr][32 + fq];
    int n_loc = w * 16 + fr;
    float hval = (z == 1) ? hks[n_loc] : 0.f;
    __syncthreads();  // xb/hks reads done; Xs region becomes kpl

    // proj MFMA per m-tile: rf from GLOBAL fp32, accumulate locally, exp, store.
    short (*kpl2)[300] = (short(*)[300])kpl;
    const float cnorm = 0.06131393394849658f;  // 266^-0.5
#pragma unroll
    for (int tr = 0; tr < 18; ++tr) {
        int row = tr * 16 + fr;
        short8 a0, a1;
        if (row < MFEAT) {
            const float* rp = rf + (size_t)row * DK;
            f32x4 v0 = *(const f32x4*)(rp + fq);
            f32x4 v1 = *(const f32x4*)(rp + fq + 4);
            f32x4 v2 = *(const f32x4*)(rp + 32 + fq);
            f32x4 v3 = *(const f32x4*)(rp + 32 + fq + 4);
            for (int j = 0; j < 4; ++j) {
                a0[j] = f2bf(v0[j]); a0[4 + j] = f2bf(v1[j]);
                a1[j] = f2bf(v2[j]); a1[4 + j] = f2bf(v3[j]);
            }
        } else {
            for (int j = 0; j < 8; ++j) { a0[j] = 0; a1[j] = 0; }
        }
        f32x4 facc = {0.f, 0.f, 0.f, 0.f};
        facc = __builtin_amdgcn_mfma_f32_16x16x32_bf16(a0, xb0, facc, 0, 0, 0);
        facc = __builtin_amdgcn_mfma_f32_16x16x32_bf16(a1, xb1, facc, 0, 0, 0);
        sv4 o;
        for (int j = 0; j < 4; ++j) {
            int m = tr * 16 + (l >> 4) * 4 + j;
            float val = (m < MFEAT) ? cnorm * (__expf(facc[j] + hval) + KERNEL_EPS) : 0.f;
            o[j] = f2bf(val);
        }
        *(sv4*)&kpl2[n_loc][tr * 16 + (l >> 4) * 4] = o;
    }
    __syncthreads();
    // coalesced copy kpl rows -> HBM
    short* outp = (z == 0) ? qp : kp;
    for (int lp = 0; lp < 9; ++lp) {
        int c = tid + lp * 256;      // 64 rows * 36 chunks
        int nn = c / 36, c8 = c % 36;
        short8 v = *(const short8*)&kpl2[nn][c8 * 8];
        *(short8*)&outp[((size_t)h * NSEQ + n0 + nn) * MPAD + c8 * 8] = v;
    }
}

// ---------------- phase A (MFMA): per-chunk sums -> bf16 KVc[(h,t,dv)][m], fp32 Ks[(h,t)][m] ----------------
__global__ __launch_bounds__(256) void chunksum_kernel(const short* __restrict__ kp,
                                                       const short* __restrict__ vh,
                                                       short* __restrict__ KVc,
                                                       float* __restrict__ Ks) {
    int t = blockIdx.x, h = blockIdx.y;
    __shared__ short kpT[288 * 72];   // [m][i-swizzled], stride 72 shorts (144B); 41.5KB
    __shared__ short Vt[64][72];      // [dv][i]
    int tid = threadIdx.x;
    int w = tid >> 6, l = tid & 63;
    int fr = l & 15, fq8 = (l >> 4) * 8;
    const short* kpb = kp + ((size_t)h * NSEQ + (size_t)t * 64) * MPAD;

    // stage kp^T: read rows coalesced, scatter to swizzled columns
    for (int lp = 0; lp < 9; ++lp) {
        int c = tid + lp * 256;       // 2304 = 64 i * 36 m-chunks
        int i = c / 36, c8 = c % 36;
        short8 v = *(const short8*)&kpb[(size_t)i * MPAD + c8 * 8];
        int i8 = i >> 3, i7 = i & 7;
        for (int jj = 0; jj < 8; ++jj) {
            int m = c8 * 8 + jj;
            int ig = i8 ^ ((m >> 3) & 7);
            kpT[m * 72 + ig * 8 + i7] = v[jj];
        }
    }
    // stage V^T
    for (int lp = 0; lp < 2; ++lp) {
        int c = tid + lp * 256;       // 512 = 64 i * 8 d-chunks
        int i = c & 63, d8 = (c >> 6) * 8;
        short8 v = *(const short8*)&vh[(size_t)(t * 64 + i) * DMODEL + h * DV + d8];
        for (int jj = 0; jj < 8; ++jj) Vt[d8 + jj][i] = v[jj];
    }
    __syncthreads();

    // D[m][dv] = sum_i kp^T[m][i] * V[i][dv]; wave w owns m-tiles {w, w+4, ...}
    f32x4 acc[5][4];
#pragma unroll
    for (int tt = 0; tt < 5; ++tt)
        for (int nf = 0; nf < 4; ++nf) acc[tt][nf] = f32x4{0, 0, 0, 0};
#pragma unroll
    for (int tt = 0; tt < 5; ++tt) {
        int tr = w + tt * 4;
        if (tr < 18) {
            int row = tr * 16 + fr;
            int swz = (row >> 3) & 7;
            short8 a0 = *(const short8*)&kpT[row * 72 + (((fq8 >> 3)) ^ swz) * 8];
            short8 a1 = *(const short8*)&kpT[row * 72 + ((4 + (fq8 >> 3)) ^ swz) * 8];
            for (int nf = 0; nf < 4; ++nf) {
                short8 b0 = *(const short8*)&Vt[nf * 16 + fr][fq8];
                short8 b1 = *(const short8*)&Vt[nf * 16 + fr][32 + fq8];
                acc[tt][nf] = __builtin_amdgcn_mfma_f32_16x16x32_bf16(a0, b0, acc[tt][nf], 0, 0, 0);
                acc[tt][nf] = __builtin_amdgcn_mfma_f32_16x16x32_bf16(a1, b1, acc[tt][nf], 0, 0, 0);
            }
        }
    }
    // Ks[m] = sum_i kp^T[m][i]
    for (int m = tid; m < MPAD; m += 256) {
        int swz = (m >> 3) & 7;
        float s = 0.f;
        for (int i8 = 0; i8 < 8; ++i8) {
            int ig = i8 ^ swz;
            for (int j = 0; j < 8; ++j) s += bf2f(kpT[m * 72 + ig * 8 + j]);
        }
        Ks[((size_t)h * NT + t) * MPAD + m] = s;
    }
    __syncthreads();  // kpT reads done; overlay kvT
    short* kvT = kpT; // [64 dv][296 m]
#pragma unroll
    for (int tt = 0; tt < 5; ++tt) {
        int tr = w + tt * 4;
        if (tr < 18) {
            for (int nf = 0; nf < 4; ++nf) {
                int dv = nf * 16 + fr;
                for (int j = 0; j < 4; ++j) {
                    int m = tr * 16 + (l >> 4) * 4 + j;
                    kvT[dv * 296 + m] = f2bf(acc[tt][nf][j]);
                }
            }
        }
    }
    __syncthreads();
    // coalesced KVc store
    for (int lp = 0; lp < 9; ++lp) {
        int c = tid + lp * 256;       // 2304 = 64 dv * 36
        int dv = c / 36, c8 = c % 36;
        short8 v = *(const short8*)&kvT[dv * 296 + c8 * 8];
        *(short8*)&KVc[(((size_t)h * NT + t) * DV + dv) * MPAD + c8 * 8] = v;
    }
}

// ---------------- fused exclusive chunk-scans, batched loads ----------------
__global__ __launch_bounds__(256) void scan_kernel(const short* __restrict__ KVc,
                                                   short* __restrict__ KVbT,
                                                   float* __restrict__ Ks,
                                                   float* __restrict__ Ktot) {
    int idx = blockIdx.x * 256 + threadIdx.x;
    const int NKV = NHEAD * DV * MPAD;       // 147456
    if (idx < NKV) {
        int h = idx / (DV * MPAD);
        int rem = idx % (DV * MPAD);
        size_t base = (size_t)h * NT * DV * MPAD + rem;
        short vals[NT];
#pragma unroll
        for (int t = 0; t < NT; ++t) vals[t] = KVc[base + (size_t)t * DV * MPAD];
        float run = 0.f;
#pragma unroll
        for (int t = 0; t < NT; ++t) {
            KVbT[base + (size_t)t * DV * MPAD] = f2bf(run);
            run += bf2f(vals[t]);
        }
    } else {
        int j = idx - NKV;
        if (j < NHEAD * MPAD) {
            int h = j / MPAD, m = j % MPAD;
            size_t base = (size_t)h * NT * MPAD + m;
            float vals[NT];
#pragma unroll
            for (int t = 0; t < NT; ++t) vals[t] = Ks[base + (size_t)t * MPAD];
            float run = 0.f;
#pragma unroll
            for (int t = 0; t < NT; ++t) {
                Ks[base + (size_t)t * MPAD] = run;
                run += vals[t];
            }
            Ktot[(size_t)h * MPAD + m] = run;
        }
    }
}

// ---------------- phase C: MFMA intra+inter+denominators; bf16 out ----------------
__global__ __launch_bounds__(256) void phasec_kernel(const short* __restrict__ qp,
                                                     const short* __restrict__ kp,
                                                     const short* __restrict__ vh,
                                                     const short* __restrict__ KVbT,
                                                     const float* __restrict__ Ks,
                                                     const float* __restrict__ Ktot,
                                                     short* __restrict__ attn) {
    int t = blockIdx.x, h = blockIdx.y;
    __shared__ short Buf[64][296];   // Kp (QK^T phase) then St (inter phase)
    __shared__ short Vt[64][72];     // [dv][i]
    __shared__ short Am[64][72];     // masked A, bf16
    __shared__ float Ksp[MPAD], Ktp[MPAD];
    __shared__ float fscale_s[64];
    int tid = threadIdx.x;
    int w = tid >> 6, l = tid & 63;
    int fr = l & 15, fq = (l >> 4) * 8;
    const short* qpb = qp + ((size_t)h * NSEQ + (size_t)t * 64) * MPAD;
    const short* kpb = kp + ((size_t)h * NSEQ + (size_t)t * 64) * MPAD;
    const short* stb = KVbT + ((size_t)h * NT + t) * DV * MPAD;

    short8 qf[9];
#pragma unroll
    for (int ks = 0; ks < 9; ++ks)
        qf[ks] = *(const short8*)&qpb[(size_t)(w * 16 + fr) * MPAD + ks * 32 + fq];

    int srow = tid >> 2, sc4 = tid & 3;
#pragma unroll
    for (int lp = 0; lp < 9; ++lp) {
        int c = sc4 + lp * 4;
        *(short8*)&Buf[srow][c * 8] = *(const short8*)&kpb[(size_t)srow * MPAD + c * 8];
    }
    // stage Vt via row reads + LDS transpose
    for (int lp = 0; lp < 2; ++lp) {
        int c = tid + lp * 256;
        int i = c & 63, d8 = (c >> 6) * 8;
        short8 v = *(const short8*)&vh[(size_t)(t * 64 + i) * DMODEL + h * DV + d8];
        for (int jj = 0; jj < 8; ++jj) Vt[d8 + jj][i] = v[jj];
    }
    for (int idx = tid; idx < MPAD; idx += 256) {
        Ksp[idx] = Ks[((size_t)h * NT + t) * MPAD + idx];
        Ktp[idx] = Ktot[(size_t)h * MPAD + idx];
    }
    // async-issue S^T loads; latency hides under QK^T MFMAs
    short8 stg[9];
#pragma unroll
    for (int lp = 0; lp < 9; ++lp) {
        int c = sc4 + lp * 4;
        stg[lp] = *(const short8*)&stb[(size_t)srow * MPAD + c * 8];
    }
    __syncthreads();

    f32x4 accA[4] = {f32x4{0,0,0,0}, f32x4{0,0,0,0}, f32x4{0,0,0,0}, f32x4{0,0,0,0}};
    f32x4 accO[4] = {f32x4{0,0,0,0}, f32x4{0,0,0,0}, f32x4{0,0,0,0}, f32x4{0,0,0,0}};
#pragma unroll 3
    for (int ks = 0; ks < 9; ++ks) {
        int ko = ks * 32 + fq;
        for (int nf = 0; nf < 4; ++nf) {
            short8 bk = *(const short8*)&Buf[nf * 16 + fr][ko];
            accA[nf] = __builtin_amdgcn_mfma_f32_16x16x32_bf16(qf[ks], bk, accA[nf], 0, 0, 0);
        }
    }
    __syncthreads();
#pragma unroll
    for (int lp = 0; lp < 9; ++lp) {
        int c = sc4 + lp * 4;
        *(short8*)&Buf[srow][c * 8] = stg[lp];
    }
    for (int nf = 0; nf < 4; ++nf) {
        int col = nf * 16 + fr;
        for (int j = 0; j < 4; ++j) {
            int row = w * 16 + (l >> 4) * 4 + j;
            Am[row][col] = (col <= row) ? f2bf(accA[nf][j]) : (short)0;
        }
    }
    __syncthreads();
#pragma unroll 3
    for (int ks = 0; ks < 9; ++ks) {
        int ko = ks * 32 + fq;
        for (int nf = 0; nf < 4; ++nf) {
            short8 bs = *(const short8*)&Buf[nf * 16 + fr][ko];
            accO[nf] = __builtin_amdgcn_mfma_f32_16x16x32_bf16(qf[ks], bs, accO[nf], 0, 0, 0);
        }
    }
#pragma unroll
    for (int ks = 0; ks < 2; ++ks) {
        int ko = ks * 32 + fq;
        short8 a = *(const short8*)&Am[w * 16 + fr][ko];
        for (int nf = 0; nf < 4; ++nf) {
            short8 b = *(const short8*)&Vt[nf * 16 + fr][ko];
            accO[nf] = __builtin_amdgcn_mfma_f32_16x16x32_bf16(a, b, accO[nf], 0, 0, 0);
        }
    }
    int di = tid >> 2, dp = tid & 3;
    float dc = 0.f, df = 0.f;
    {
        const short* amrow = &Am[di][dp * 16];
        short8 s0 = *(const short8*)amrow;
        short8 s1 = *(const short8*)(amrow + 8);
        for (int j2 = 0; j2 < 8; ++j2) dc += bf2f(s0[j2]) + bf2f(s1[j2]);
    }
#pragma unroll
    for (int c8 = 0; c8 < 9; ++c8) {
        int m = dp * 72 + c8 * 8;
        short8 qv = *(const short8*)&qpb[(size_t)di * MPAD + m];
        for (int j2 = 0; j2 < 8; ++j2) {
            float qq = bf2f(qv[j2]);
            dc += qq * Ksp[m + j2];
            df += qq * Ktp[m + j2];
        }
    }
    dc += __shfl_xor(dc, 1); dc += __shfl_xor(dc, 2);
    df += __shfl_xor(df, 1); df += __shfl_xor(df, 2);
    if (dp == 0) {
        float dst = df;
        if (fabsf(dst) <= NORM_STAB) dst += 2.f * NORM_STAB;
        fscale_s[di] = (1.f / dc) / dst;
    }
    __syncthreads();
    for (int nf = 0; nf < 4; ++nf) {
        int col = nf * 16 + fr;
        for (int j = 0; j < 4; ++j) {
            int row = w * 16 + (l >> 4) * 4 + j;
            attn[((size_t)t * 64 + row) * DMODEL + h * DV + col] =
                f2bf(accO[nf][j] * fscale_s[row]);
        }
    }
}

// ---------------- final GEMM with bias + residual (A is bf16) ----------------
__global__ __launch_bounds__(256) void fgemm_kernel(const short* __restrict__ A,
                                                    const float* __restrict__ B,
                                                    float* __restrict__ C,
                                                    const float* __restrict__ bias,
                                                    const float* __restrict__ residual) {
    __shared__ short As[64][40];
    __shared__ short Bs[64][40];
    int bm = blockIdx.y * 64, bn = blockIdx.x * 64;
    int tid = threadIdx.x;
    int wid = tid >> 6, lane = tid & 63;
    f32x4 acc[4] = {f32x4{0,0,0,0}, f32x4{0,0,0,0}, f32x4{0,0,0,0}, f32x4{0,0,0,0}};
    int ar = tid >> 2, akq = tid & 3;
    int bkk = tid >> 3, bng = tid & 7;
    for (int k0 = 0; k0 < DMODEL; k0 += 32) {
        {
            const short* src = A + (size_t)(bm + ar) * DMODEL + k0 + akq * 8;
            *(short8*)&As[ar][akq * 8] = *(const short8*)src;
        }
        {
            const float* src = B + (size_t)(k0 + bkk) * DMODEL + bn + bng * 8;
            f32x4 v0 = *(const f32x4*)src;
            f32x4 v1 = *(const f32x4*)(src + 4);
            for (int j = 0; j < 4; ++j) {
                Bs[bng * 8 + j][bkk] = f2bf(v0[j]);
                Bs[bng * 8 + 4 + j][bkk] = f2bf(v1[j]);
            }
        }
        __syncthreads();
        int row = wid * 16 + (lane & 15);
        int koff = (lane >> 4) * 8;
        short8 a = *(const short8*)&As[row][koff];
        for (int nf = 0; nf < 4; ++nf) {
            int col = nf * 16 + (lane & 15);
            short8 b = *(const short8*)&Bs[col][koff];
            acc[nf] = __builtin_amdgcn_mfma_f32_16x16x32_bf16(a, b, acc[nf], 0, 0, 0);
        }
        __syncthreads();
    }
    for (int nf = 0; nf < 4; ++nf) {
        int col = bn + nf * 16 + (lane & 15);
        for (int j = 0; j < 4; ++j) {
            int row = bm + wid * 16 + (lane >> 4) * 4 + j;
            C[(size_t)row * DMODEL + col] =
                acc[nf][j] + bias[col] + residual[(size_t)row * DMODEL + col];
        }
    }
}

extern "C" void kernel_launch(void* const* d_in, const int* in_sizes, int n_in,
                              void* d_out, int out_size, void* d_ws, size_t ws_size,
                              hipStream_t stream) {
    const float* q = (const float*)d_in[0];
    const float* k = (const float*)d_in[1];
    const float* v = (const float*)d_in[2];
    const float* Wq = (const float*)d_in[3];
    const float* Wk = (const float*)d_in[4];
    const float* Wv = (const float*)d_in[5];
    const float* Wfc = (const float*)d_in[6];
    const float* bfc = (const float*)d_in[7];
    const float* gamma = (const float*)d_in[8];
    const float* beta = (const float*)d_in[9];
    const float* rf = (const float*)d_in[10];
    float* out = (float*)d_out;

    float* ws = (float*)d_ws;
    short* attn = (short*)ws;                              // bf16 2048*512
    short* vhb = attn + (size_t)NSEQ * DMODEL;             // bf16 2048*512
    short* qp = vhb + (size_t)NSEQ * DMODEL;               // bf16 8*2048*288
    short* kp = qp + (size_t)NHEAD * NSEQ * MPAD;
    short* KVc = kp + (size_t)NHEAD * NSEQ * MPAD;         // bf16 8*32*64*288
    short* KVbT = KVc + (size_t)NHEAD * NT * DV * MPAD;
    float* Ks = (float*)(KVbT + (size_t)NHEAD * NT * DV * MPAD);   // fp32 8*32*288
    float* Ktot = Ks + (size_t)NHEAD * NT * MPAD;          // 8*288

    dim3 gq(NT, NHEAD, 3);
    qkvfeat_kernel<<<gq, 256, 0, stream>>>(q, k, v, Wq, Wk, Wv, gamma, beta, rf,
                                           vhb, qp, kp);
    dim3 ga(NT, NHEAD);
    chunksum_kernel<<<ga, 256, 0, stream>>>(kp, vhb, KVc, Ks);
    int scan_threads = NHEAD * DV * MPAD + NHEAD * MPAD;
    scan_kernel<<<(scan_threads + 255) / 256, 256, 0, stream>>>(KVc, KVbT, Ks, Ktot);
    dim3 gc(NT, NHEAD);
    phasec_kernel<<<gc, 256, 0, stream>>>(qp, kp, vhb, KVbT, Ks, Ktot, attn);
    dim3 g(DMODEL / 64, NSEQ / 64);
    fgemm_kernel<<<g, 256, 0, stream>>>(attn, Wfc, out, bfc, q);
}

// Round 17
// 80.071 us; speedup vs baseline: 1.2995x; 1.0861x over previous
//
#include <hip/hip_runtime.h>
#include <hip/hip_bf16.h>
#include <math.h>

#define DMODEL 512
#define NSEQ 2048
#define NHEAD 8
#define DK 64
#define DV 64
#define MFEAT 266
#define MPAD 288        // padded feature dim for bf16 MFMA (zero tail), mult of 32
#define NT 32           // number of chunks (chunk = 64)
#define LN_EPS 1e-6f
#define KERNEL_EPS 1e-4f
#define NORM_STAB 1e-6f
#define SCALE 0.21022410381342863f  // 512^-0.25

typedef __attribute__((ext_vector_type(8))) short short8;
typedef __attribute__((ext_vector_type(4))) short sv4;
typedef __attribute__((ext_vector_type(4))) float f32x4;

// Compiler-native bf16 RNE cast (fuses to v_cvt_pk_bf16_f32; m240: don't hand-roll)
__device__ inline short f2bf(float f) {
    return (short)__bfloat16_as_ushort(__float2bfloat16(f));
}
__device__ inline float bf2f(short s) {
    unsigned u = ((unsigned)(unsigned short)s) << 16;
    return __builtin_bit_cast(float, u);
}

// ---------------- prep: transpose+cast weights to bf16 [n][k]; SCALE folded into Wq/Wk ----------------
// grid (8 kt, 8 ntile, 4 weight). Removes qkvfeat/fgemm's B transpose-scatter (R16: 6.9M conflicts).
__global__ __launch_bounds__(256) void prep_kernel(const float* __restrict__ Wq,
                                                   const float* __restrict__ Wk,
                                                   const float* __restrict__ Wv,
                                                   const float* __restrict__ Wfc,
                                                   short* __restrict__ Wqt,
                                                   short* __restrict__ Wkt,
                                                   short* __restrict__ Wvt,
                                                   short* __restrict__ Wfct) {
    __shared__ short T[64][65];
    int k0 = blockIdx.x * 64, n0 = blockIdx.y * 64, wsel = blockIdx.z;
    const float* W = (wsel == 0) ? Wq : (wsel == 1) ? Wk : (wsel == 2) ? Wv : Wfc;
    short* Wt = (wsel == 0) ? Wqt : (wsel == 1) ? Wkt : (wsel == 2) ? Wvt : Wfct;
    float scale = (wsel <= 1) ? SCALE : 1.f;
    int tid = threadIdx.x;
    for (int lp = 0; lp < 4; ++lp) {
        int c = tid + lp * 256;             // 1024 = 64 k-rows * 16 n-quads
        int kk = c >> 4, q4 = (c & 15) * 4;
        f32x4 v = *(const f32x4*)&W[(size_t)(k0 + kk) * DMODEL + n0 + q4];
        for (int j = 0; j < 4; ++j) T[q4 + j][kk] = f2bf(v[j] * scale);
    }
    __syncthreads();
    for (int lp = 0; lp < 2; ++lp) {
        int c = tid + lp * 256;             // 512 = 64 n-rows * 8 k-chunks
        int nn = c >> 3, c8 = c & 7;
        short8 v = *(const short8*)&T[nn][c8 * 8];
        *(short8*)&Wt[(size_t)(n0 + nn) * DMODEL + k0 + c8 * 8] = v;
    }
}

// ============ fused QKV GEMM + random-feature map ============
// grid (nt=32, h=8, z=3). B from pre-transposed bf16 Wt: vectorized conflict-free staging.
__global__ __launch_bounds__(256) void qkvfeat_kernel(const float* __restrict__ qx,
                                                      const float* __restrict__ kx,
                                                      const float* __restrict__ vx,
                                                      const short* __restrict__ Wqt,
                                                      const short* __restrict__ Wkt,
                                                      const short* __restrict__ Wvt,
                                                      const float* __restrict__ gamma,
                                                      const float* __restrict__ beta,
                                                      const float* __restrict__ rf,
                                                      short* __restrict__ vh,
                                                      short* __restrict__ qp,
                                                      short* __restrict__ kp) {
    __shared__ __align__(16) char smem[38656];
    auto As = (short(*)[40])smem;              // GEMM phase
    auto Bs = (short(*)[40])(smem + 5120);
    auto Xs = (short(*)[72])smem;              // feat input (overlays As/Bs after GEMM)
    short* kpl = (short*)smem;                 // 64x300 output staging (overlays Xs after xb read)
    float* hks = (float*)(smem + 38400);       // 64 floats

    int z = blockIdx.z;
    const float* A = (z == 0) ? qx : (z == 1) ? kx : vx;
    const short* Bt = (z == 0) ? Wqt : (z == 1) ? Wkt : Wvt;
    int nt = blockIdx.x, h = blockIdx.y;
    int bm = nt * 64, bn = h * 64, n0 = nt * 64;
    int tid = threadIdx.x;
    int wid = tid >> 6, lane = tid & 63;
    f32x4 acc[4] = {f32x4{0,0,0,0}, f32x4{0,0,0,0}, f32x4{0,0,0,0}, f32x4{0,0,0,0}};
    int ar = tid >> 2, akq = tid & 3;
    float lnm = 0.f, lnr = 0.f;
    if (z == 0) {
        // per-quad LN stats for row bm+ar (4 threads per row)
        const float* xr = qx + (size_t)(bm + ar) * DMODEL + akq * 128;
        float s = 0.f, ss = 0.f;
#pragma unroll 4
        for (int i = 0; i < 128; i += 4) {
            f32x4 vv = *(const f32x4*)(xr + i);
            s += vv[0] + vv[1] + vv[2] + vv[3];
            ss += vv[0]*vv[0] + vv[1]*vv[1] + vv[2]*vv[2] + vv[3]*vv[3];
        }
        s += __shfl_xor(s, 1); s += __shfl_xor(s, 2);
        ss += __shfl_xor(ss, 1); ss += __shfl_xor(ss, 2);
        float m = s / (float)DMODEL;
        float var = ss / (float)DMODEL - m * m;
        lnm = m;
        lnr = rsqrtf(var + LN_EPS);
    }
    for (int k0 = 0; k0 < DMODEL; k0 += 32) {
        {
            const float* src = A + (size_t)(bm + ar) * DMODEL + k0 + akq * 8;
            f32x4 v0 = *(const f32x4*)src;
            f32x4 v1 = *(const f32x4*)(src + 4);
            short8 sv;
            if (z == 0) {
                f32x4 g0 = *(const f32x4*)&gamma[k0 + akq * 8];
                f32x4 g1 = *(const f32x4*)&gamma[k0 + akq * 8 + 4];
                f32x4 bb0 = *(const f32x4*)&beta[k0 + akq * 8];
                f32x4 bb1 = *(const f32x4*)&beta[k0 + akq * 8 + 4];
                for (int j = 0; j < 4; ++j) {
                    sv[j] = f2bf((v0[j] - lnm) * lnr * g0[j] + bb0[j]);
                    sv[4 + j] = f2bf((v1[j] - lnm) * lnr * g1[j] + bb1[j]);
                }
            } else {
                for (int j = 0; j < 4; ++j) { sv[j] = f2bf(v0[j]); sv[4 + j] = f2bf(v1[j]); }
            }
            *(short8*)&As[ar][akq * 8] = sv;
        }
        {
            // vectorized conflict-free B staging from bf16 [n][k]
            *(short8*)&Bs[ar][akq * 8] =
                *(const short8*)&Bt[(size_t)(bn + ar) * DMODEL + k0 + akq * 8];
        }
        __syncthreads();
        int row = wid * 16 + (lane & 15);
        int koff = (lane >> 4) * 8;
        short8 a = *(const short8*)&As[row][koff];
        for (int nf = 0; nf < 4; ++nf) {
            int col = nf * 16 + (lane & 15);
            short8 b = *(const short8*)&Bs[col][koff];
            acc[nf] = __builtin_amdgcn_mfma_f32_16x16x32_bf16(a, b, acc[nf], 0, 0, 0);
        }
        __syncthreads();
    }
    if (z == 2) {
        // V path: write vh and exit
        for (int nf = 0; nf < 4; ++nf) {
            int col = bn + nf * 16 + (lane & 15);
            for (int j = 0; j < 4; ++j) {
                int row = bm + wid * 16 + (lane >> 4) * 4 + j;
                vh[(size_t)row * DMODEL + col] = f2bf(acc[nf][j]);
            }
        }
        return;
    }
    // ---- feat phase: C tile -> Xs (bf16); overlays dead As/Bs ----
    for (int nf = 0; nf < 4; ++nf) {
        int col = nf * 16 + (lane & 15);
        for (int j = 0; j < 4; ++j) {
            int row = wid * 16 + (lane >> 4) * 4 + j;
            Xs[row][col] = f2bf(acc[nf][j]);
        }
    }
    if (z == 1) {
        // local h_k per row from fp32 accumulators
        for (int j = 0; j < 4; ++j) {
            float ss = 0.f;
            for (int nf = 0; nf < 4; ++nf) ss += acc[nf][j] * acc[nf][j];
            for (int o = 1; o < 16; o <<= 1) ss += __shfl_xor(ss, o);
            if ((lane & 15) == 0) hks[wid * 16 + (lane >> 4) * 4 + j] = -0.5f * ss;
        }
    }
    __syncthreads();

    int w = wid, l = lane;
    int fr = l & 15, fq = (l >> 4) * 8;
    short8 xb0 = *(const short8*)&Xs[w * 16 + fr][fq];
    short8 xb1 = *(const short8*)&Xs[w * 16 + fr][32 + fq];
    int n_loc = w * 16 + fr;
    float hval = (z == 1) ? hks[n_loc] : 0.f;
    __syncthreads();  // xb/hks reads done; Xs region becomes kpl

    // proj MFMA per m-tile: rf from GLOBAL fp32, accumulate locally, exp, store.
    short (*kpl2)[300] = (short(*)[300])kpl;
    const float cnorm = 0.06131393394849658f;  // 266^-0.5
#pragma unroll
    for (int tr = 0; tr < 18; ++tr) {
        int row = tr * 16 + fr;
        short8 a0, a1;
        if (row < MFEAT) {
            const float* rp = rf + (size_t)row * DK;
            f32x4 v0 = *(const f32x4*)(rp + fq);
            f32x4 v1 = *(const f32x4*)(rp + fq + 4);
            f32x4 v2 = *(const f32x4*)(rp + 32 + fq);
            f32x4 v3 = *(const f32x4*)(rp + 32 + fq + 4);
            for (int j = 0; j < 4; ++j) {
                a0[j] = f2bf(v0[j]); a0[4 + j] = f2bf(v1[j]);
                a1[j] = f2bf(v2[j]); a1[4 + j] = f2bf(v3[j]);
            }
        } else {
            for (int j = 0; j < 8; ++j) { a0[j] = 0; a1[j] = 0; }
        }
        f32x4 facc = {0.f, 0.f, 0.f, 0.f};
        facc = __builtin_amdgcn_mfma_f32_16x16x32_bf16(a0, xb0, facc, 0, 0, 0);
        facc = __builtin_amdgcn_mfma_f32_16x16x32_bf16(a1, xb1, facc, 0, 0, 0);
        sv4 o;
        for (int j = 0; j < 4; ++j) {
            int m = tr * 16 + (l >> 4) * 4 + j;
            float val = (m < MFEAT) ? cnorm * (__expf(facc[j] + hval) + KERNEL_EPS) : 0.f;
            o[j] = f2bf(val);
        }
        *(sv4*)&kpl2[n_loc][tr * 16 + (l >> 4) * 4] = o;
    }
    __syncthreads();
    // coalesced copy kpl rows -> HBM
    short* outp = (z == 0) ? qp : kp;
    for (int lp = 0; lp < 9; ++lp) {
        int c = tid + lp * 256;      // 64 rows * 36 chunks
        int nn = c / 36, c8 = c % 36;
        short8 v = *(const short8*)&kpl2[nn][c8 * 8];
        *(short8*)&outp[((size_t)h * NSEQ + n0 + nn) * MPAD + c8 * 8] = v;
    }
}

// ---------------- phase A (MFMA): per-chunk sums -> bf16 KVc[(h,t,dv)][m], fp32 Ks[(h,t)][m] ----------------
__global__ __launch_bounds__(256) void chunksum_kernel(const short* __restrict__ kp,
                                                       const short* __restrict__ vh,
                                                       short* __restrict__ KVc,
                                                       float* __restrict__ Ks) {
    int t = blockIdx.x, h = blockIdx.y;
    __shared__ short kpT[288 * 72];   // [m][i-swizzled], stride 72 shorts (144B); 41.5KB
    __shared__ short Vt[64][72];      // [dv][i]
    int tid = threadIdx.x;
    int w = tid >> 6, l = tid & 63;
    int fr = l & 15, fq8 = (l >> 4) * 8;
    const short* kpb = kp + ((size_t)h * NSEQ + (size_t)t * 64) * MPAD;

    // stage kp^T: read rows coalesced, scatter to swizzled columns
    for (int lp = 0; lp < 9; ++lp) {
        int c = tid + lp * 256;       // 2304 = 64 i * 36 m-chunks
        int i = c / 36, c8 = c % 36;
        short8 v = *(const short8*)&kpb[(size_t)i * MPAD + c8 * 8];
        int i8 = i >> 3, i7 = i & 7;
        for (int jj = 0; jj < 8; ++jj) {
            int m = c8 * 8 + jj;
            int ig = i8 ^ ((m >> 3) & 7);
            kpT[m * 72 + ig * 8 + i7] = v[jj];
        }
    }
    // stage V^T
    for (int lp = 0; lp < 2; ++lp) {
        int c = tid + lp * 256;       // 512 = 64 i * 8 d-chunks
        int i = c & 63, d8 = (c >> 6) * 8;
        short8 v = *(const short8*)&vh[(size_t)(t * 64 + i) * DMODEL + h * DV + d8];
        for (int jj = 0; jj < 8; ++jj) Vt[d8 + jj][i] = v[jj];
    }
    __syncthreads();

    // D[m][dv] = sum_i kp^T[m][i] * V[i][dv]; wave w owns m-tiles {w, w+4, ...}
    f32x4 acc[5][4];
#pragma unroll
    for (int tt = 0; tt < 5; ++tt)
        for (int nf = 0; nf < 4; ++nf) acc[tt][nf] = f32x4{0, 0, 0, 0};
#pragma unroll
    for (int tt = 0; tt < 5; ++tt) {
        int tr = w + tt * 4;
        if (tr < 18) {
            int row = tr * 16 + fr;
            int swz = (row >> 3) & 7;
            short8 a0 = *(const short8*)&kpT[row * 72 + (((fq8 >> 3)) ^ swz) * 8];
            short8 a1 = *(const short8*)&kpT[row * 72 + ((4 + (fq8 >> 3)) ^ swz) * 8];
            for (int nf = 0; nf < 4; ++nf) {
                short8 b0 = *(const short8*)&Vt[nf * 16 + fr][fq8];
                short8 b1 = *(const short8*)&Vt[nf * 16 + fr][32 + fq8];
                acc[tt][nf] = __builtin_amdgcn_mfma_f32_16x16x32_bf16(a0, b0, acc[tt][nf], 0, 0, 0);
                acc[tt][nf] = __builtin_amdgcn_mfma_f32_16x16x32_bf16(a1, b1, acc[tt][nf], 0, 0, 0);
            }
        }
    }
    // Ks[m] = sum_i kp^T[m][i]
    for (int m = tid; m < MPAD; m += 256) {
        int swz = (m >> 3) & 7;
        float s = 0.f;
        for (int i8 = 0; i8 < 8; ++i8) {
            int ig = i8 ^ swz;
            for (int j = 0; j < 8; ++j) s += bf2f(kpT[m * 72 + ig * 8 + j]);
        }
        Ks[((size_t)h * NT + t) * MPAD + m] = s;
    }
    __syncthreads();  // kpT reads done; overlay kvT
    short* kvT = kpT; // [64 dv][296 m]
#pragma unroll
    for (int tt = 0; tt < 5; ++tt) {
        int tr = w + tt * 4;
        if (tr < 18) {
            for (int nf = 0; nf < 4; ++nf) {
                int dv = nf * 16 + fr;
                for (int j = 0; j < 4; ++j) {
                    int m = tr * 16 + (l >> 4) * 4 + j;
                    kvT[dv * 296 + m] = f2bf(acc[tt][nf][j]);
                }
            }
        }
    }
    __syncthreads();
    // coalesced KVc store
    for (int lp = 0; lp < 9; ++lp) {
        int c = tid + lp * 256;       // 2304 = 64 dv * 36
        int dv = c / 36, c8 = c % 36;
        short8 v = *(const short8*)&kvT[dv * 296 + c8 * 8];
        *(short8*)&KVc[(((size_t)h * NT + t) * DV + dv) * MPAD + c8 * 8] = v;
    }
}

// ---------------- fused exclusive chunk-scans, batched loads ----------------
__global__ __launch_bounds__(256) void scan_kernel(const short* __restrict__ KVc,
                                                   short* __restrict__ KVbT,
                                                   float* __restrict__ Ks,
                                                   float* __restrict__ Ktot) {
    int idx = blockIdx.x * 256 + threadIdx.x;
    const int NKV = NHEAD * DV * MPAD;       // 147456
    if (idx < NKV) {
        int h = idx / (DV * MPAD);
        int rem = idx % (DV * MPAD);
        size_t base = (size_t)h * NT * DV * MPAD + rem;
        short vals[NT];
#pragma unroll
        for (int t = 0; t < NT; ++t) vals[t] = KVc[base + (size_t)t * DV * MPAD];
        float run = 0.f;
#pragma unroll
        for (int t = 0; t < NT; ++t) {
            KVbT[base + (size_t)t * DV * MPAD] = f2bf(run);
            run += bf2f(vals[t]);
        }
    } else {
        int j = idx - NKV;
        if (j < NHEAD * MPAD) {
            int h = j / MPAD, m = j % MPAD;
            size_t base = (size_t)h * NT * MPAD + m;
            float vals[NT];
#pragma unroll
            for (int t = 0; t < NT; ++t) vals[t] = Ks[base + (size_t)t * MPAD];
            float run = 0.f;
#pragma unroll
            for (int t = 0; t < NT; ++t) {
                Ks[base + (size_t)t * MPAD] = run;
                run += vals[t];
            }
            Ktot[(size_t)h * MPAD + m] = run;
        }
    }
}

// ---------------- phase C: MFMA intra+inter+denominators; bf16 out ----------------
__global__ __launch_bounds__(256) void phasec_kernel(const short* __restrict__ qp,
                                                     const short* __restrict__ kp,
                                                     const short* __restrict__ vh,
                                                     const short* __restrict__ KVbT,
                                                     const float* __restrict__ Ks,
                                                     const float* __restrict__ Ktot,
                                                     short* __restrict__ attn) {
    int t = blockIdx.x, h = blockIdx.y;
    __shared__ short Buf[64][296];   // Kp (QK^T phase) then St (inter phase)
    __shared__ short Vt[64][72];     // [dv][i]
    __shared__ short Am[64][72];     // masked A, bf16
    __shared__ float Ksp[MPAD], Ktp[MPAD];
    __shared__ float fscale_s[64];
    int tid = threadIdx.x;
    int w = tid >> 6, l = tid & 63;
    int fr = l & 15, fq = (l >> 4) * 8;
    const short* qpb = qp + ((size_t)h * NSEQ + (size_t)t * 64) * MPAD;
    const short* kpb = kp + ((size_t)h * NSEQ + (size_t)t * 64) * MPAD;
    const short* stb = KVbT + ((size_t)h * NT + t) * DV * MPAD;

    short8 qf[9];
#pragma unroll
    for (int ks = 0; ks < 9; ++ks)
        qf[ks] = *(const short8*)&qpb[(size_t)(w * 16 + fr) * MPAD + ks * 32 + fq];

    int srow = tid >> 2, sc4 = tid & 3;
#pragma unroll
    for (int lp = 0; lp < 9; ++lp) {
        int c = sc4 + lp * 4;
        *(short8*)&Buf[srow][c * 8] = *(const short8*)&kpb[(size_t)srow * MPAD + c * 8];
    }
    // stage Vt via row reads + LDS transpose
    for (int lp = 0; lp < 2; ++lp) {
        int c = tid + lp * 256;
        int i = c & 63, d8 = (c >> 6) * 8;
        short8 v = *(const short8*)&vh[(size_t)(t * 64 + i) * DMODEL + h * DV + d8];
        for (int jj = 0; jj < 8; ++jj) Vt[d8 + jj][i] = v[jj];
    }
    for (int idx = tid; idx < MPAD; idx += 256) {
        Ksp[idx] = Ks[((size_t)h * NT + t) * MPAD + idx];
        Ktp[idx] = Ktot[(size_t)h * MPAD + idx];
    }
    // async-issue S^T loads; latency hides under QK^T MFMAs
    short8 stg[9];
#pragma unroll
    for (int lp = 0; lp < 9; ++lp) {
        int c = sc4 + lp * 4;
        stg[lp] = *(const short8*)&stb[(size_t)srow * MPAD + c * 8];
    }
    __syncthreads();

    f32x4 accA[4] = {f32x4{0,0,0,0}, f32x4{0,0,0,0}, f32x4{0,0,0,0}, f32x4{0,0,0,0}};
    f32x4 accO[4] = {f32x4{0,0,0,0}, f32x4{0,0,0,0}, f32x4{0,0,0,0}, f32x4{0,0,0,0}};
#pragma unroll 3
    for (int ks = 0; ks < 9; ++ks) {
        int ko = ks * 32 + fq;
        for (int nf = 0; nf < 4; ++nf) {
            short8 bk = *(const short8*)&Buf[nf * 16 + fr][ko];
            accA[nf] = __builtin_amdgcn_mfma_f32_16x16x32_bf16(qf[ks], bk, accA[nf], 0, 0, 0);
        }
    }
    __syncthreads();
#pragma unroll
    for (int lp = 0; lp < 9; ++lp) {
        int c = sc4 + lp * 4;
        *(short8*)&Buf[srow][c * 8] = stg[lp];
    }
    for (int nf = 0; nf < 4; ++nf) {
        int col = nf * 16 + fr;
        for (int j = 0; j < 4; ++j) {
            int row = w * 16 + (l >> 4) * 4 + j;
            Am[row][col] = (col <= row) ? f2bf(accA[nf][j]) : (short)0;
        }
    }
    __syncthreads();
#pragma unroll 3
    for (int ks = 0; ks < 9; ++ks) {
        int ko = ks * 32 + fq;
        for (int nf = 0; nf < 4; ++nf) {
            short8 bs = *(const short8*)&Buf[nf * 16 + fr][ko];
            accO[nf] = __builtin_amdgcn_mfma_f32_16x16x32_bf16(qf[ks], bs, accO[nf], 0, 0, 0);
        }
    }
#pragma unroll
    for (int ks = 0; ks < 2; ++ks) {
        int ko = ks * 32 + fq;
        short8 a = *(const short8*)&Am[w * 16 + fr][ko];
        for (int nf = 0; nf < 4; ++nf) {
            short8 b = *(const short8*)&Vt[nf * 16 + fr][ko];
            accO[nf] = __builtin_amdgcn_mfma_f32_16x16x32_bf16(a, b, accO[nf], 0, 0, 0);
        }
    }
    int di = tid >> 2, dp = tid & 3;
    float dc = 0.f, df = 0.f;
    {
        const short* amrow = &Am[di][dp * 16];
        short8 s0 = *(const short8*)amrow;
        short8 s1 = *(const short8*)(amrow + 8);
        for (int j2 = 0; j2 < 8; ++j2) dc += bf2f(s0[j2]) + bf2f(s1[j2]);
    }
#pragma unroll
    for (int c8 = 0; c8 < 9; ++c8) {
        int m = dp * 72 + c8 * 8;
        short8 qv = *(const short8*)&qpb[(size_t)di * MPAD + m];
        for (int j2 = 0; j2 < 8; ++j2) {
            float qq = bf2f(qv[j2]);
            dc += qq * Ksp[m + j2];
            df += qq * Ktp[m + j2];
        }
    }
    dc += __shfl_xor(dc, 1); dc += __shfl_xor(dc, 2);
    df += __shfl_xor(df, 1); df += __shfl_xor(df, 2);
    if (dp == 0) {
        float dst = df;
        if (fabsf(dst) <= NORM_STAB) dst += 2.f * NORM_STAB;
        fscale_s[di] = (1.f / dc) / dst;
    }
    __syncthreads();
    for (int nf = 0; nf < 4; ++nf) {
        int col = nf * 16 + fr;
        for (int j = 0; j < 4; ++j) {
            int row = w * 16 + (l >> 4) * 4 + j;
            attn[((size_t)t * 64 + row) * DMODEL + h * DV + col] =
                f2bf(accO[nf][j] * fscale_s[row]);
        }
    }
}

// ---------------- final GEMM with bias + residual (A bf16, B pre-transposed bf16) ----------------
__global__ __launch_bounds__(256) void fgemm_kernel(const short* __restrict__ A,
                                                    const short* __restrict__ Bt,
                                                    float* __restrict__ C,
                                                    const float* __restrict__ bias,
                                                    const float* __restrict__ residual) {
    __shared__ short As[64][40];
    __shared__ short Bs[64][40];
    int bm = blockIdx.y * 64, bn = blockIdx.x * 64;
    int tid = threadIdx.x;
    int wid = tid >> 6, lane = tid & 63;
    f32x4 acc[4] = {f32x4{0,0,0,0}, f32x4{0,0,0,0}, f32x4{0,0,0,0}, f32x4{0,0,0,0}};
    int ar = tid >> 2, akq = tid & 3;
    for (int k0 = 0; k0 < DMODEL; k0 += 32) {
        *(short8*)&As[ar][akq * 8] =
            *(const short8*)&A[(size_t)(bm + ar) * DMODEL + k0 + akq * 8];
        *(short8*)&Bs[ar][akq * 8] =
            *(const short8*)&Bt[(size_t)(bn + ar) * DMODEL + k0 + akq * 8];
        __syncthreads();
        int row = wid * 16 + (lane & 15);
        int koff = (lane >> 4) * 8;
        short8 a = *(const short8*)&As[row][koff];
        for (int nf = 0; nf < 4; ++nf) {
            int col = nf * 16 + (lane & 15);
            short8 b = *(const short8*)&Bs[col][koff];
            acc[nf] = __builtin_amdgcn_mfma_f32_16x16x32_bf16(a, b, acc[nf], 0, 0, 0);
        }
        __syncthreads();
    }
    for (int nf = 0; nf < 4; ++nf) {
        int col = bn + nf * 16 + (lane & 15);
        for (int j = 0; j < 4; ++j) {
            int row = bm + wid * 16 + (lane >> 4) * 4 + j;
            C[(size_t)row * DMODEL + col] =
                acc[nf][j] + bias[col] + residual[(size_t)row * DMODEL + col];
        }
    }
}

extern "C" void kernel_launch(void* const* d_in, const int* in_sizes, int n_in,
                              void* d_out, int out_size, void* d_ws, size_t ws_size,
                              hipStream_t stream) {
    const float* q = (const float*)d_in[0];
    const float* k = (const float*)d_in[1];
    const float* v = (const float*)d_in[2];
    const float* Wq = (const float*)d_in[3];
    const float* Wk = (const float*)d_in[4];
    const float* Wv = (const float*)d_in[5];
    const float* Wfc = (const float*)d_in[6];
    const float* bfc = (const float*)d_in[7];
    const float* gamma = (const float*)d_in[8];
    const float* beta = (const float*)d_in[9];
    const float* rf = (const float*)d_in[10];
    float* out = (float*)d_out;

    float* ws = (float*)d_ws;
    short* attn = (short*)ws;                              // bf16 2048*512
    short* vhb = attn + (size_t)NSEQ * DMODEL;             // bf16 2048*512
    short* qp = vhb + (size_t)NSEQ * DMODEL;               // bf16 8*2048*288
    short* kp = qp + (size_t)NHEAD * NSEQ * MPAD;
    short* KVc = kp + (size_t)NHEAD * NSEQ * MPAD;         // bf16 8*32*64*288
    short* KVbT = KVc + (size_t)NHEAD * NT * DV * MPAD;
    float* Ks = (float*)(KVbT + (size_t)NHEAD * NT * DV * MPAD);   // fp32 8*32*288
    float* Ktot = Ks + (size_t)NHEAD * NT * MPAD;          // 8*288
    short* Wqt = (short*)(Ktot + (size_t)NHEAD * MPAD);    // bf16 512*512 each
    short* Wkt = Wqt + (size_t)DMODEL * DMODEL;
    short* Wvt = Wkt + (size_t)DMODEL * DMODEL;
    short* Wfct = Wvt + (size_t)DMODEL * DMODEL;

    dim3 gp(8, 8, 4);
    prep_kernel<<<gp, 256, 0, stream>>>(Wq, Wk, Wv, Wfc, Wqt, Wkt, Wvt, Wfct);
    dim3 gq(NT, NHEAD, 3);
    qkvfeat_kernel<<<gq, 256, 0, stream>>>(q, k, v, Wqt, Wkt, Wvt, gamma, beta, rf,
                                           vhb, qp, kp);
    dim3 ga(NT, NHEAD);
    chunksum_kernel<<<ga, 256, 0, stream>>>(kp, vhb, KVc, Ks);
    int scan_threads = NHEAD * DV * MPAD + NHEAD * MPAD;
    scan_kernel<<<(scan_threads + 255) / 256, 256, 0, stream>>>(KVc, KVbT, Ks, Ktot);
    dim3 gc(NT, NHEAD);
    phasec_kernel<<<gc, 256, 0, stream>>>(qp, kp, vhb, KVbT, Ks, Ktot, attn);
    dim3 g(DMODEL / 64, NSEQ / 64);
    fgemm_kernel<<<g, 256, 0, stream>>>(attn, Wfct, out, bfc, q);
}

// Round 18
// 76.739 us; speedup vs baseline: 1.3559x; 1.0434x over previous
//
#include <hip/hip_runtime.h>
#include <hip/hip_bf16.h>
#include <math.h>

#define DMODEL 512
#define NSEQ 2048
#define NHEAD 8
#define DK 64
#define DV 64
#define MFEAT 266
#define MPAD 288        // padded feature dim for bf16 MFMA (zero tail), mult of 32
#define NT 32           // number of chunks (chunk = 64)
#define LN_EPS 1e-6f
#define KERNEL_EPS 1e-4f
#define NORM_STAB 1e-6f
#define SCALE 0.21022410381342863f  // 512^-0.25

typedef __attribute__((ext_vector_type(8))) short short8;
typedef __attribute__((ext_vector_type(4))) short sv4;
typedef __attribute__((ext_vector_type(4))) float f32x4;

// Compiler-native bf16 RNE cast (fuses to v_cvt_pk_bf16_f32; m240: don't hand-roll)
__device__ inline short f2bf(float f) {
    return (short)__bfloat16_as_ushort(__float2bfloat16(f));
}
__device__ inline float bf2f(short s) {
    unsigned u = ((unsigned)(unsigned short)s) << 16;
    return __builtin_bit_cast(float, u);
}

// ---------------- prep: transpose+cast weights to bf16 [n][k]; SCALE folded into Wq/Wk ----------------
__global__ __launch_bounds__(256) void prep_kernel(const float* __restrict__ Wq,
                                                   const float* __restrict__ Wk,
                                                   const float* __restrict__ Wv,
                                                   const float* __restrict__ Wfc,
                                                   short* __restrict__ Wqt,
                                                   short* __restrict__ Wkt,
                                                   short* __restrict__ Wvt,
                                                   short* __restrict__ Wfct) {
    __shared__ short T[64][65];
    int k0 = blockIdx.x * 64, n0 = blockIdx.y * 64, wsel = blockIdx.z;
    const float* W = (wsel == 0) ? Wq : (wsel == 1) ? Wk : (wsel == 2) ? Wv : Wfc;
    short* Wt = (wsel == 0) ? Wqt : (wsel == 1) ? Wkt : (wsel == 2) ? Wvt : Wfct;
    float scale = (wsel <= 1) ? SCALE : 1.f;
    int tid = threadIdx.x;
    for (int lp = 0; lp < 4; ++lp) {
        int c = tid + lp * 256;             // 1024 = 64 k-rows * 16 n-quads
        int kk = c >> 4, q4 = (c & 15) * 4;
        f32x4 v = *(const f32x4*)&W[(size_t)(k0 + kk) * DMODEL + n0 + q4];
        for (int j = 0; j < 4; ++j) T[q4 + j][kk] = f2bf(v[j] * scale);
    }
    __syncthreads();
    for (int lp = 0; lp < 2; ++lp) {
        int c = tid + lp * 256;             // 512 = 64 n-rows * 8 k-chunks
        int nn = c >> 3, c8 = c & 7;
        short8 v = *(const short8*)&T[nn][c8 * 8];
        *(short8*)&Wt[(size_t)(n0 + nn) * DMODEL + k0 + c8 * 8] = v;
    }
}

// ============ fused QKV GEMM + random-feature map ============
// grid (nt=32, h=8, z=3). GEMM K-loop: register-prefetch + double-buffered LDS,
// ONE barrier per iter (T14: global loads stay in flight across the barrier).
__global__ __launch_bounds__(256) void qkvfeat_kernel(const float* __restrict__ qx,
                                                      const float* __restrict__ kx,
                                                      const float* __restrict__ vx,
                                                      const short* __restrict__ Wqt,
                                                      const short* __restrict__ Wkt,
                                                      const short* __restrict__ Wvt,
                                                      const float* __restrict__ gamma,
                                                      const float* __restrict__ beta,
                                                      const float* __restrict__ rf,
                                                      short* __restrict__ vh,
                                                      short* __restrict__ qp,
                                                      short* __restrict__ kp) {
    __shared__ __align__(16) char smem[38656];
    auto AsB = (short(*)[40])smem;             // [128][40]: double-buffered A
    auto BsB = (short(*)[40])(smem + 10240);   // [128][40]: double-buffered B
    auto Xs = (short(*)[72])smem;              // feat input (overlays after GEMM)
    short* kpl = (short*)smem;                 // 64x300 output staging
    float* hks = (float*)(smem + 38400);       // 64 floats

    int z = blockIdx.z;
    const float* A = (z == 0) ? qx : (z == 1) ? kx : vx;
    const short* Bt = (z == 0) ? Wqt : (z == 1) ? Wkt : Wvt;
    int nt = blockIdx.x, h = blockIdx.y;
    int bm = nt * 64, bn = h * 64, n0 = nt * 64;
    int tid = threadIdx.x;
    int wid = tid >> 6, lane = tid & 63;
    f32x4 acc[4] = {f32x4{0,0,0,0}, f32x4{0,0,0,0}, f32x4{0,0,0,0}, f32x4{0,0,0,0}};
    int ar = tid >> 2, akq = tid & 3;
    float lnm = 0.f, lnr = 0.f;
    if (z == 0) {
        const float* xr = qx + (size_t)(bm + ar) * DMODEL + akq * 128;
        float s = 0.f, ss = 0.f;
#pragma unroll 4
        for (int i = 0; i < 128; i += 4) {
            f32x4 vv = *(const f32x4*)(xr + i);
            s += vv[0] + vv[1] + vv[2] + vv[3];
            ss += vv[0]*vv[0] + vv[1]*vv[1] + vv[2]*vv[2] + vv[3]*vv[3];
        }
        s += __shfl_xor(s, 1); s += __shfl_xor(s, 2);
        ss += __shfl_xor(ss, 1); ss += __shfl_xor(ss, 2);
        float m = s / (float)DMODEL;
        float var = ss / (float)DMODEL - m * m;
        lnm = m;
        lnr = rsqrtf(var + LN_EPS);
    }
    auto loadA = [&](int k0) -> short8 {
        const float* src = A + (size_t)(bm + ar) * DMODEL + k0 + akq * 8;
        f32x4 v0 = *(const f32x4*)src;
        f32x4 v1 = *(const f32x4*)(src + 4);
        short8 sv;
        if (z == 0) {
            f32x4 g0 = *(const f32x4*)&gamma[k0 + akq * 8];
            f32x4 g1 = *(const f32x4*)&gamma[k0 + akq * 8 + 4];
            f32x4 bb0 = *(const f32x4*)&beta[k0 + akq * 8];
            f32x4 bb1 = *(const f32x4*)&beta[k0 + akq * 8 + 4];
            for (int j = 0; j < 4; ++j) {
                sv[j] = f2bf((v0[j] - lnm) * lnr * g0[j] + bb0[j]);
                sv[4 + j] = f2bf((v1[j] - lnm) * lnr * g1[j] + bb1[j]);
            }
        } else {
            for (int j = 0; j < 4; ++j) { sv[j] = f2bf(v0[j]); sv[4 + j] = f2bf(v1[j]); }
        }
        return sv;
    };
    auto loadB = [&](int k0) -> short8 {
        return *(const short8*)&Bt[(size_t)(bn + ar) * DMODEL + k0 + akq * 8];
    };
    short8 aReg = loadA(0), bReg = loadB(0);
    int buf = 0;
#pragma unroll 2
    for (int k0 = 0; k0 < DMODEL; k0 += 32) {
        *(short8*)&AsB[buf * 64 + ar][akq * 8] = aReg;
        *(short8*)&BsB[buf * 64 + ar][akq * 8] = bReg;
        __syncthreads();
        if (k0 + 32 < DMODEL) { aReg = loadA(k0 + 32); bReg = loadB(k0 + 32); }
        int row = buf * 64 + wid * 16 + (lane & 15);
        int koff = (lane >> 4) * 8;
        short8 a = *(const short8*)&AsB[row][koff];
        for (int nf = 0; nf < 4; ++nf) {
            int col = buf * 64 + nf * 16 + (lane & 15);
            short8 b = *(const short8*)&BsB[col][koff];
            acc[nf] = __builtin_amdgcn_mfma_f32_16x16x32_bf16(a, b, acc[nf], 0, 0, 0);
        }
        buf ^= 1;
    }
    __syncthreads();   // all waves done with LDS before feat-phase overlay / exit
    if (z == 2) {
        for (int nf = 0; nf < 4; ++nf) {
            int col = bn + nf * 16 + (lane & 15);
            for (int j = 0; j < 4; ++j) {
                int row = bm + wid * 16 + (lane >> 4) * 4 + j;
                vh[(size_t)row * DMODEL + col] = f2bf(acc[nf][j]);
            }
        }
        return;
    }
    // ---- feat phase: C tile -> Xs (bf16) ----
    for (int nf = 0; nf < 4; ++nf) {
        int col = nf * 16 + (lane & 15);
        for (int j = 0; j < 4; ++j) {
            int row = wid * 16 + (lane >> 4) * 4 + j;
            Xs[row][col] = f2bf(acc[nf][j]);
        }
    }
    if (z == 1) {
        for (int j = 0; j < 4; ++j) {
            float ss = 0.f;
            for (int nf = 0; nf < 4; ++nf) ss += acc[nf][j] * acc[nf][j];
            for (int o = 1; o < 16; o <<= 1) ss += __shfl_xor(ss, o);
            if ((lane & 15) == 0) hks[wid * 16 + (lane >> 4) * 4 + j] = -0.5f * ss;
        }
    }
    __syncthreads();

    int w = wid, l = lane;
    int fr = l & 15, fq = (l >> 4) * 8;
    short8 xb0 = *(const short8*)&Xs[w * 16 + fr][fq];
    short8 xb1 = *(const short8*)&Xs[w * 16 + fr][32 + fq];
    int n_loc = w * 16 + fr;
    float hval = (z == 1) ? hks[n_loc] : 0.f;
    __syncthreads();  // xb/hks reads done; Xs region becomes kpl

    short (*kpl2)[300] = (short(*)[300])kpl;
    const float cnorm = 0.06131393394849658f;  // 266^-0.5
#pragma unroll
    for (int tr = 0; tr < 18; ++tr) {
        int row = tr * 16 + fr;
        short8 a0, a1;
        if (row < MFEAT) {
            const float* rp = rf + (size_t)row * DK;
            f32x4 v0 = *(const f32x4*)(rp + fq);
            f32x4 v1 = *(const f32x4*)(rp + fq + 4);
            f32x4 v2 = *(const f32x4*)(rp + 32 + fq);
            f32x4 v3 = *(const f32x4*)(rp + 32 + fq + 4);
            for (int j = 0; j < 4; ++j) {
                a0[j] = f2bf(v0[j]); a0[4 + j] = f2bf(v1[j]);
                a1[j] = f2bf(v2[j]); a1[4 + j] = f2bf(v3[j]);
            }
        } else {
            for (int j = 0; j < 8; ++j) { a0[j] = 0; a1[j] = 0; }
        }
        f32x4 facc = {0.f, 0.f, 0.f, 0.f};
        facc = __builtin_amdgcn_mfma_f32_16x16x32_bf16(a0, xb0, facc, 0, 0, 0);
        facc = __builtin_amdgcn_mfma_f32_16x16x32_bf16(a1, xb1, facc, 0, 0, 0);
        sv4 o;
        for (int j = 0; j < 4; ++j) {
            int m = tr * 16 + (l >> 4) * 4 + j;
            float val = (m < MFEAT) ? cnorm * (__expf(facc[j] + hval) + KERNEL_EPS) : 0.f;
            o[j] = f2bf(val);
        }
        *(sv4*)&kpl2[n_loc][tr * 16 + (l >> 4) * 4] = o;
    }
    __syncthreads();
    short* outp = (z == 0) ? qp : kp;
    for (int lp = 0; lp < 9; ++lp) {
        int c = tid + lp * 256;      // 64 rows * 36 chunks
        int nn = c / 36, c8 = c % 36;
        short8 v = *(const short8*)&kpl2[nn][c8 * 8];
        *(short8*)&outp[((size_t)h * NSEQ + n0 + nn) * MPAD + c8 * 8] = v;
    }
}

// ---------------- phase A (MFMA): per-chunk sums -> bf16 KVc[(h,t,dv)][m], fp32 Ks[(h,t)][m] ----------------
__global__ __launch_bounds__(256) void chunksum_kernel(const short* __restrict__ kp,
                                                       const short* __restrict__ vh,
                                                       short* __restrict__ KVc,
                                                       float* __restrict__ Ks) {
    int t = blockIdx.x, h = blockIdx.y;
    __shared__ short kpT[288 * 72];   // [m][i-swizzled], stride 72 shorts (144B); 41.5KB
    __shared__ short Vt[64][72];      // [dv][i]
    int tid = threadIdx.x;
    int w = tid >> 6, l = tid & 63;
    int fr = l & 15, fq8 = (l >> 4) * 8;
    const short* kpb = kp + ((size_t)h * NSEQ + (size_t)t * 64) * MPAD;

    for (int lp = 0; lp < 9; ++lp) {
        int c = tid + lp * 256;       // 2304 = 64 i * 36 m-chunks
        int i = c / 36, c8 = c % 36;
        short8 v = *(const short8*)&kpb[(size_t)i * MPAD + c8 * 8];
        int i8 = i >> 3, i7 = i & 7;
        for (int jj = 0; jj < 8; ++jj) {
            int m = c8 * 8 + jj;
            int ig = i8 ^ ((m >> 3) & 7);
            kpT[m * 72 + ig * 8 + i7] = v[jj];
        }
    }
    for (int lp = 0; lp < 2; ++lp) {
        int c = tid + lp * 256;       // 512 = 64 i * 8 d-chunks
        int i = c & 63, d8 = (c >> 6) * 8;
        short8 v = *(const short8*)&vh[(size_t)(t * 64 + i) * DMODEL + h * DV + d8];
        for (int jj = 0; jj < 8; ++jj) Vt[d8 + jj][i] = v[jj];
    }
    __syncthreads();

    f32x4 acc[5][4];
#pragma unroll
    for (int tt = 0; tt < 5; ++tt)
        for (int nf = 0; nf < 4; ++nf) acc[tt][nf] = f32x4{0, 0, 0, 0};
#pragma unroll
    for (int tt = 0; tt < 5; ++tt) {
        int tr = w + tt * 4;
        if (tr < 18) {
            int row = tr * 16 + fr;
            int swz = (row >> 3) & 7;
            short8 a0 = *(const short8*)&kpT[row * 72 + (((fq8 >> 3)) ^ swz) * 8];
            short8 a1 = *(const short8*)&kpT[row * 72 + ((4 + (fq8 >> 3)) ^ swz) * 8];
            for (int nf = 0; nf < 4; ++nf) {
                short8 b0 = *(const short8*)&Vt[nf * 16 + fr][fq8];
                short8 b1 = *(const short8*)&Vt[nf * 16 + fr][32 + fq8];
                acc[tt][nf] = __builtin_amdgcn_mfma_f32_16x16x32_bf16(a0, b0, acc[tt][nf], 0, 0, 0);
                acc[tt][nf] = __builtin_amdgcn_mfma_f32_16x16x32_bf16(a1, b1, acc[tt][nf], 0, 0, 0);
            }
        }
    }
    for (int m = tid; m < MPAD; m += 256) {
        int swz = (m >> 3) & 7;
        float s = 0.f;
        for (int i8 = 0; i8 < 8; ++i8) {
            int ig = i8 ^ swz;
            for (int j = 0; j < 8; ++j) s += bf2f(kpT[m * 72 + ig * 8 + j]);
        }
        Ks[((size_t)h * NT + t) * MPAD + m] = s;
    }
    __syncthreads();  // kpT reads done; overlay kvT
    short* kvT = kpT; // [64 dv][296 m]
#pragma unroll
    for (int tt = 0; tt < 5; ++tt) {
        int tr = w + tt * 4;
        if (tr < 18) {
            for (int nf = 0; nf < 4; ++nf) {
                int dv = nf * 16 + fr;
                for (int j = 0; j < 4; ++j) {
                    int m = tr * 16 + (l >> 4) * 4 + j;
                    kvT[dv * 296 + m] = f2bf(acc[tt][nf][j]);
                }
            }
        }
    }
    __syncthreads();
    for (int lp = 0; lp < 9; ++lp) {
        int c = tid + lp * 256;       // 2304 = 64 dv * 36
        int dv = c / 36, c8 = c % 36;
        short8 v = *(const short8*)&kvT[dv * 296 + c8 * 8];
        *(short8*)&KVc[(((size_t)h * NT + t) * DV + dv) * MPAD + c8 * 8] = v;
    }
}

// ---------------- fused exclusive chunk-scans, batched loads ----------------
__global__ __launch_bounds__(256) void scan_kernel(const short* __restrict__ KVc,
                                                   short* __restrict__ KVbT,
                                                   float* __restrict__ Ks,
                                                   float* __restrict__ Ktot) {
    int idx = blockIdx.x * 256 + threadIdx.x;
    const int NKV = NHEAD * DV * MPAD;       // 147456
    if (idx < NKV) {
        int h = idx / (DV * MPAD);
        int rem = idx % (DV * MPAD);
        size_t base = (size_t)h * NT * DV * MPAD + rem;
        short vals[NT];
#pragma unroll
        for (int t = 0; t < NT; ++t) vals[t] = KVc[base + (size_t)t * DV * MPAD];
        float run = 0.f;
#pragma unroll
        for (int t = 0; t < NT; ++t) {
            KVbT[base + (size_t)t * DV * MPAD] = f2bf(run);
            run += bf2f(vals[t]);
        }
    } else {
        int j = idx - NKV;
        if (j < NHEAD * MPAD) {
            int h = j / MPAD, m = j % MPAD;
            size_t base = (size_t)h * NT * MPAD + m;
            float vals[NT];
#pragma unroll
            for (int t = 0; t < NT; ++t) vals[t] = Ks[base + (size_t)t * MPAD];
            float run = 0.f;
#pragma unroll
            for (int t = 0; t < NT; ++t) {
                Ks[base + (size_t)t * MPAD] = run;
                run += vals[t];
            }
            Ktot[(size_t)h * MPAD + m] = run;
        }
    }
}

// ---------------- phase C: MFMA intra+inter+denominators; bf16 out ----------------
__global__ __launch_bounds__(256) void phasec_kernel(const short* __restrict__ qp,
                                                     const short* __restrict__ kp,
                                                     const short* __restrict__ vh,
                                                     const short* __restrict__ KVbT,
                                                     const float* __restrict__ Ks,
                                                     const float* __restrict__ Ktot,
                                                     short* __restrict__ attn) {
    int t = blockIdx.x, h = blockIdx.y;
    __shared__ short Buf[64][296];   // Kp (QK^T phase) then St (inter phase)
    __shared__ short Vt[64][72];     // [dv][i]
    __shared__ short Am[64][72];     // masked A, bf16
    __shared__ float Ksp[MPAD], Ktp[MPAD];
    __shared__ float fscale_s[64];
    int tid = threadIdx.x;
    int w = tid >> 6, l = tid & 63;
    int fr = l & 15, fq = (l >> 4) * 8;
    const short* qpb = qp + ((size_t)h * NSEQ + (size_t)t * 64) * MPAD;
    const short* kpb = kp + ((size_t)h * NSEQ + (size_t)t * 64) * MPAD;
    const short* stb = KVbT + ((size_t)h * NT + t) * DV * MPAD;

    short8 qf[9];
#pragma unroll
    for (int ks = 0; ks < 9; ++ks)
        qf[ks] = *(const short8*)&qpb[(size_t)(w * 16 + fr) * MPAD + ks * 32 + fq];

    int srow = tid >> 2, sc4 = tid & 3;
#pragma unroll
    for (int lp = 0; lp < 9; ++lp) {
        int c = sc4 + lp * 4;
        *(short8*)&Buf[srow][c * 8] = *(const short8*)&kpb[(size_t)srow * MPAD + c * 8];
    }
    for (int lp = 0; lp < 2; ++lp) {
        int c = tid + lp * 256;
        int i = c & 63, d8 = (c >> 6) * 8;
        short8 v = *(const short8*)&vh[(size_t)(t * 64 + i) * DMODEL + h * DV + d8];
        for (int jj = 0; jj < 8; ++jj) Vt[d8 + jj][i] = v[jj];
    }
    for (int idx = tid; idx < MPAD; idx += 256) {
        Ksp[idx] = Ks[((size_t)h * NT + t) * MPAD + idx];
        Ktp[idx] = Ktot[(size_t)h * MPAD + idx];
    }
    short8 stg[9];
#pragma unroll
    for (int lp = 0; lp < 9; ++lp) {
        int c = sc4 + lp * 4;
        stg[lp] = *(const short8*)&stb[(size_t)srow * MPAD + c * 8];
    }
    __syncthreads();

    f32x4 accA[4] = {f32x4{0,0,0,0}, f32x4{0,0,0,0}, f32x4{0,0,0,0}, f32x4{0,0,0,0}};
    f32x4 accO[4] = {f32x4{0,0,0,0}, f32x4{0,0,0,0}, f32x4{0,0,0,0}, f32x4{0,0,0,0}};
#pragma unroll 3
    for (int ks = 0; ks < 9; ++ks) {
        int ko = ks * 32 + fq;
        for (int nf = 0; nf < 4; ++nf) {
            short8 bk = *(const short8*)&Buf[nf * 16 + fr][ko];
            accA[nf] = __builtin_amdgcn_mfma_f32_16x16x32_bf16(qf[ks], bk, accA[nf], 0, 0, 0);
        }
    }
    __syncthreads();
#pragma unroll
    for (int lp = 0; lp < 9; ++lp) {
        int c = sc4 + lp * 4;
        *(short8*)&Buf[srow][c * 8] = stg[lp];
    }
    for (int nf = 0; nf < 4; ++nf) {
        int col = nf * 16 + fr;
        for (int j = 0; j < 4; ++j) {
            int row = w * 16 + (l >> 4) * 4 + j;
            Am[row][col] = (col <= row) ? f2bf(accA[nf][j]) : (short)0;
        }
    }
    __syncthreads();
#pragma unroll 3
    for (int ks = 0; ks < 9; ++ks) {
        int ko = ks * 32 + fq;
        for (int nf = 0; nf < 4; ++nf) {
            short8 bs = *(const short8*)&Buf[nf * 16 + fr][ko];
            accO[nf] = __builtin_amdgcn_mfma_f32_16x16x32_bf16(qf[ks], bs, accO[nf], 0, 0, 0);
        }
    }
#pragma unroll
    for (int ks = 0; ks < 2; ++ks) {
        int ko = ks * 32 + fq;
        short8 a = *(const short8*)&Am[w * 16 + fr][ko];
        for (int nf = 0; nf < 4; ++nf) {
            short8 b = *(const short8*)&Vt[nf * 16 + fr][ko];
            accO[nf] = __builtin_amdgcn_mfma_f32_16x16x32_bf16(a, b, accO[nf], 0, 0, 0);
        }
    }
    int di = tid >> 2, dp = tid & 3;
    float dc = 0.f, df = 0.f;
    {
        const short* amrow = &Am[di][dp * 16];
        short8 s0 = *(const short8*)amrow;
        short8 s1 = *(const short8*)(amrow + 8);
        for (int j2 = 0; j2 < 8; ++j2) dc += bf2f(s0[j2]) + bf2f(s1[j2]);
    }
#pragma unroll
    for (int c8 = 0; c8 < 9; ++c8) {
        int m = dp * 72 + c8 * 8;
        short8 qv = *(const short8*)&qpb[(size_t)di * MPAD + m];
        for (int j2 = 0; j2 < 8; ++j2) {
            float qq = bf2f(qv[j2]);
            dc += qq * Ksp[m + j2];
            df += qq * Ktp[m + j2];
        }
    }
    dc += __shfl_xor(dc, 1); dc += __shfl_xor(dc, 2);
    df += __shfl_xor(df, 1); df += __shfl_xor(df, 2);
    if (dp == 0) {
        float dst = df;
        if (fabsf(dst) <= NORM_STAB) dst += 2.f * NORM_STAB;
        fscale_s[di] = (1.f / dc) / dst;
    }
    __syncthreads();
    for (int nf = 0; nf < 4; ++nf) {
        int col = nf * 16 + fr;
        for (int j = 0; j < 4; ++j) {
            int row = w * 16 + (l >> 4) * 4 + j;
            attn[((size_t)t * 64 + row) * DMODEL + h * DV + col] =
                f2bf(accO[nf][j] * fscale_s[row]);
        }
    }
}

// ---------------- final GEMM with bias + residual (A bf16, B pre-transposed bf16; pipelined) ----------------
__global__ __launch_bounds__(256) void fgemm_kernel(const short* __restrict__ A,
                                                    const short* __restrict__ Bt,
                                                    float* __restrict__ C,
                                                    const float* __restrict__ bias,
                                                    const float* __restrict__ residual) {
    __shared__ short AsB[128][40];
    __shared__ short BsB[128][40];
    int bm = blockIdx.y * 64, bn = blockIdx.x * 64;
    int tid = threadIdx.x;
    int wid = tid >> 6, lane = tid & 63;
    f32x4 acc[4] = {f32x4{0,0,0,0}, f32x4{0,0,0,0}, f32x4{0,0,0,0}, f32x4{0,0,0,0}};
    int ar = tid >> 2, akq = tid & 3;
    short8 aReg = *(const short8*)&A[(size_t)(bm + ar) * DMODEL + akq * 8];
    short8 bReg = *(const short8*)&Bt[(size_t)(bn + ar) * DMODEL + akq * 8];
    int buf = 0;
#pragma unroll 2
    for (int k0 = 0; k0 < DMODEL; k0 += 32) {
        *(short8*)&AsB[buf * 64 + ar][akq * 8] = aReg;
        *(short8*)&BsB[buf * 64 + ar][akq * 8] = bReg;
        __syncthreads();
        if (k0 + 32 < DMODEL) {
            aReg = *(const short8*)&A[(size_t)(bm + ar) * DMODEL + k0 + 32 + akq * 8];
            bReg = *(const short8*)&Bt[(size_t)(bn + ar) * DMODEL + k0 + 32 + akq * 8];
        }
        int row = buf * 64 + wid * 16 + (lane & 15);
        int koff = (lane >> 4) * 8;
        short8 a = *(const short8*)&AsB[row][koff];
        for (int nf = 0; nf < 4; ++nf) {
            int col = buf * 64 + nf * 16 + (lane & 15);
            short8 b = *(const short8*)&BsB[col][koff];
            acc[nf] = __builtin_amdgcn_mfma_f32_16x16x32_bf16(a, b, acc[nf], 0, 0, 0);
        }
        buf ^= 1;
    }
    for (int nf = 0; nf < 4; ++nf) {
        int col = bn + nf * 16 + (lane & 15);
        for (int j = 0; j < 4; ++j) {
            int row = bm + wid * 16 + (lane >> 4) * 4 + j;
            C[(size_t)row * DMODEL + col] =
                acc[nf][j] + bias[col] + residual[(size_t)row * DMODEL + col];
        }
    }
}

extern "C" void kernel_launch(void* const* d_in, const int* in_sizes, int n_in,
                              void* d_out, int out_size, void* d_ws, size_t ws_size,
                              hipStream_t stream) {
    const float* q = (const float*)d_in[0];
    const float* k = (const float*)d_in[1];
    const float* v = (const float*)d_in[2];
    const float* Wq = (const float*)d_in[3];
    const float* Wk = (const float*)d_in[4];
    const float* Wv = (const float*)d_in[5];
    const float* Wfc = (const float*)d_in[6];
    const float* bfc = (const float*)d_in[7];
    const float* gamma = (const float*)d_in[8];
    const float* beta = (const float*)d_in[9];
    const float* rf = (const float*)d_in[10];
    float* out = (float*)d_out;

    float* ws = (float*)d_ws;
    short* attn = (short*)ws;                              // bf16 2048*512
    short* vhb = attn + (size_t)NSEQ * DMODEL;             // bf16 2048*512
    short* qp = vhb + (size_t)NSEQ * DMODEL;               // bf16 8*2048*288
    short* kp = qp + (size_t)NHEAD * NSEQ * MPAD;
    short* KVc = kp + (size_t)NHEAD * NSEQ * MPAD;         // bf16 8*32*64*288
    short* KVbT = KVc + (size_t)NHEAD * NT * DV * MPAD;
    float* Ks = (float*)(KVbT + (size_t)NHEAD * NT * DV * MPAD);   // fp32 8*32*288
    float* Ktot = Ks + (size_t)NHEAD * NT * MPAD;          // 8*288
    short* Wqt = (short*)(Ktot + (size_t)NHEAD * MPAD);    // bf16 512*512 each
    short* Wkt = Wqt + (size_t)DMODEL * DMODEL;
    short* Wvt = Wkt + (size_t)DMODEL * DMODEL;
    short* Wfct = Wvt + (size_t)DMODEL * DMODEL;

    dim3 gp(8, 8, 4);
    prep_kernel<<<gp, 256, 0, stream>>>(Wq, Wk, Wv, Wfc, Wqt, Wkt, Wvt, Wfct);
    dim3 gq(NT, NHEAD, 3);
    qkvfeat_kernel<<<gq, 256, 0, stream>>>(q, k, v, Wqt, Wkt, Wvt, gamma, beta, rf,
                                           vhb, qp, kp);
    dim3 ga(NT, NHEAD);
    chunksum_kernel<<<ga, 256, 0, stream>>>(kp, vhb, KVc, Ks);
    int scan_threads = NHEAD * DV * MPAD + NHEAD * MPAD;
    scan_kernel<<<(scan_threads + 255) / 256, 256, 0, stream>>>(KVc, KVbT, Ks, Ktot);
    dim3 gc(NT, NHEAD);
    phasec_kernel<<<gc, 256, 0, stream>>>(qp, kp, vhb, KVbT, Ks, Ktot, attn);
    dim3 g(DMODEL / 64, NSEQ / 64);
    fgemm_kernel<<<g, 256, 0, stream>>>(attn, Wfct, out, bfc, q);
}

// Round 19
// 69.874 us; speedup vs baseline: 1.4891x; 1.0982x over previous
//
#include <hip/hip_runtime.h>
#include <hip/hip_bf16.h>
#include <math.h>

#define DMODEL 512
#define NSEQ 2048
#define NHEAD 8
#define DK 64
#define DV 64
#define MFEAT 266
#define MPAD 288        // padded feature dim for bf16 MFMA (zero tail), mult of 32
#define NT 32           // number of chunks (chunk = 64)
#define LN_EPS 1e-6f
#define KERNEL_EPS 1e-4f
#define NORM_STAB 1e-6f
#define SCALE 0.21022410381342863f  // 512^-0.25

typedef __attribute__((ext_vector_type(8))) short short8;
typedef __attribute__((ext_vector_type(4))) short sv4;
typedef __attribute__((ext_vector_type(4))) float f32x4;

// Compiler-native bf16 RNE cast (fuses to v_cvt_pk_bf16_f32; m240: don't hand-roll)
__device__ inline short f2bf(float f) {
    return (short)__bfloat16_as_ushort(__float2bfloat16(f));
}
__device__ inline float bf2f(short s) {
    unsigned u = ((unsigned)(unsigned short)s) << 16;
    return __builtin_bit_cast(float, u);
}

// ---------------- prep: weights -> bf16 [n][k] (SCALE folded); rf -> bf16 [MPAD][64] zero-padded ----------------
__global__ __launch_bounds__(256) void prep_kernel(const float* __restrict__ Wq,
                                                   const float* __restrict__ Wk,
                                                   const float* __restrict__ Wv,
                                                   const float* __restrict__ Wfc,
                                                   const float* __restrict__ rf,
                                                   short* __restrict__ Wqt,
                                                   short* __restrict__ Wkt,
                                                   short* __restrict__ Wvt,
                                                   short* __restrict__ Wfct,
                                                   short* __restrict__ rfb) {
    int wsel = blockIdx.z;
    int tid = threadIdx.x;
    if (wsel == 4) {
        // rf conversion: one (0, y) slice handles 36 rows of 64
        if (blockIdx.x != 0) return;
        int r0 = blockIdx.y * 36;
        for (int lp = 0; lp < 9; ++lp) {
            int c = tid + lp * 256;          // 2304 = 36 rows * 64 cols
            int r = r0 + c / 64, d = c % 64;
            float v = (r < MFEAT) ? rf[(size_t)r * DK + d] : 0.f;
            rfb[(size_t)r * DK + d] = f2bf(v);
        }
        return;
    }
    __shared__ short T[64][65];
    int k0 = blockIdx.x * 64, n0 = blockIdx.y * 64;
    const float* W = (wsel == 0) ? Wq : (wsel == 1) ? Wk : (wsel == 2) ? Wv : Wfc;
    short* Wt = (wsel == 0) ? Wqt : (wsel == 1) ? Wkt : (wsel == 2) ? Wvt : Wfct;
    float scale = (wsel <= 1) ? SCALE : 1.f;
    for (int lp = 0; lp < 4; ++lp) {
        int c = tid + lp * 256;             // 1024 = 64 k-rows * 16 n-quads
        int kk = c >> 4, q4 = (c & 15) * 4;
        f32x4 v = *(const f32x4*)&W[(size_t)(k0 + kk) * DMODEL + n0 + q4];
        for (int j = 0; j < 4; ++j) T[q4 + j][kk] = f2bf(v[j] * scale);
    }
    __syncthreads();
    for (int lp = 0; lp < 2; ++lp) {
        int c = tid + lp * 256;             // 512 = 64 n-rows * 8 k-chunks
        int nn = c >> 3, c8 = c & 7;
        short8 v = *(const short8*)&T[nn][c8 * 8];
        *(short8*)&Wt[(size_t)(n0 + nn) * DMODEL + k0 + c8 * 8] = v;
    }
}

// ============ fused QKV GEMM + random-feature map ============
// grid (nt=32, h=8, z=3). GEMM: reg-prefetch + dbuf LDS, one barrier/iter.
// feat: rf fragments from pre-converted bf16 rfb (2 short8 loads/tr, zero cvt).
__global__ __launch_bounds__(256) void qkvfeat_kernel(const float* __restrict__ qx,
                                                      const float* __restrict__ kx,
                                                      const float* __restrict__ vx,
                                                      const short* __restrict__ Wqt,
                                                      const short* __restrict__ Wkt,
                                                      const short* __restrict__ Wvt,
                                                      const float* __restrict__ gamma,
                                                      const float* __restrict__ beta,
                                                      const short* __restrict__ rfb,
                                                      short* __restrict__ vh,
                                                      short* __restrict__ qp,
                                                      short* __restrict__ kp) {
    __shared__ __align__(16) char smem[38656];
    auto AsB = (short(*)[40])smem;             // [128][40]: double-buffered A
    auto BsB = (short(*)[40])(smem + 10240);   // [128][40]: double-buffered B
    auto Xs = (short(*)[72])smem;              // feat input (overlays after GEMM)
    short* kpl = (short*)smem;                 // 64x300 output staging
    float* hks = (float*)(smem + 38400);       // 64 floats

    int z = blockIdx.z;
    const float* A = (z == 0) ? qx : (z == 1) ? kx : vx;
    const short* Bt = (z == 0) ? Wqt : (z == 1) ? Wkt : Wvt;
    int nt = blockIdx.x, h = blockIdx.y;
    int bm = nt * 64, bn = h * 64, n0 = nt * 64;
    int tid = threadIdx.x;
    int wid = tid >> 6, lane = tid & 63;
    f32x4 acc[4] = {f32x4{0,0,0,0}, f32x4{0,0,0,0}, f32x4{0,0,0,0}, f32x4{0,0,0,0}};
    int ar = tid >> 2, akq = tid & 3;
    float lnm = 0.f, lnr = 0.f;
    if (z == 0) {
        const float* xr = qx + (size_t)(bm + ar) * DMODEL + akq * 128;
        float s = 0.f, ss = 0.f;
#pragma unroll 4
        for (int i = 0; i < 128; i += 4) {
            f32x4 vv = *(const f32x4*)(xr + i);
            s += vv[0] + vv[1] + vv[2] + vv[3];
            ss += vv[0]*vv[0] + vv[1]*vv[1] + vv[2]*vv[2] + vv[3]*vv[3];
        }
        s += __shfl_xor(s, 1); s += __shfl_xor(s, 2);
        ss += __shfl_xor(ss, 1); ss += __shfl_xor(ss, 2);
        float m = s / (float)DMODEL;
        float var = ss / (float)DMODEL - m * m;
        lnm = m;
        lnr = rsqrtf(var + LN_EPS);
    }
    auto loadA = [&](int k0) -> short8 {
        const float* src = A + (size_t)(bm + ar) * DMODEL + k0 + akq * 8;
        f32x4 v0 = *(const f32x4*)src;
        f32x4 v1 = *(const f32x4*)(src + 4);
        short8 sv;
        if (z == 0) {
            f32x4 g0 = *(const f32x4*)&gamma[k0 + akq * 8];
            f32x4 g1 = *(const f32x4*)&gamma[k0 + akq * 8 + 4];
            f32x4 bb0 = *(const f32x4*)&beta[k0 + akq * 8];
            f32x4 bb1 = *(const f32x4*)&beta[k0 + akq * 8 + 4];
            for (int j = 0; j < 4; ++j) {
                sv[j] = f2bf((v0[j] - lnm) * lnr * g0[j] + bb0[j]);
                sv[4 + j] = f2bf((v1[j] - lnm) * lnr * g1[j] + bb1[j]);
            }
        } else {
            for (int j = 0; j < 4; ++j) { sv[j] = f2bf(v0[j]); sv[4 + j] = f2bf(v1[j]); }
        }
        return sv;
    };
    auto loadB = [&](int k0) -> short8 {
        return *(const short8*)&Bt[(size_t)(bn + ar) * DMODEL + k0 + akq * 8];
    };
    short8 aReg = loadA(0), bReg = loadB(0);
    int buf = 0;
#pragma unroll 2
    for (int k0 = 0; k0 < DMODEL; k0 += 32) {
        *(short8*)&AsB[buf * 64 + ar][akq * 8] = aReg;
        *(short8*)&BsB[buf * 64 + ar][akq * 8] = bReg;
        __syncthreads();
        if (k0 + 32 < DMODEL) { aReg = loadA(k0 + 32); bReg = loadB(k0 + 32); }
        int row = buf * 64 + wid * 16 + (lane & 15);
        int koff = (lane >> 4) * 8;
        short8 a = *(const short8*)&AsB[row][koff];
        for (int nf = 0; nf < 4; ++nf) {
            int col = buf * 64 + nf * 16 + (lane & 15);
            short8 b = *(const short8*)&BsB[col][koff];
            acc[nf] = __builtin_amdgcn_mfma_f32_16x16x32_bf16(a, b, acc[nf], 0, 0, 0);
        }
        buf ^= 1;
    }
    __syncthreads();   // all waves done with LDS before feat-phase overlay / exit
    if (z == 2) {
        for (int nf = 0; nf < 4; ++nf) {
            int col = bn + nf * 16 + (lane & 15);
            for (int j = 0; j < 4; ++j) {
                int row = bm + wid * 16 + (lane >> 4) * 4 + j;
                vh[(size_t)row * DMODEL + col] = f2bf(acc[nf][j]);
            }
        }
        return;
    }
    // ---- feat phase: C tile -> Xs (bf16) ----
    for (int nf = 0; nf < 4; ++nf) {
        int col = nf * 16 + (lane & 15);
        for (int j = 0; j < 4; ++j) {
            int row = wid * 16 + (lane >> 4) * 4 + j;
            Xs[row][col] = f2bf(acc[nf][j]);
        }
    }
    if (z == 1) {
        for (int j = 0; j < 4; ++j) {
            float ss = 0.f;
            for (int nf = 0; nf < 4; ++nf) ss += acc[nf][j] * acc[nf][j];
            for (int o = 1; o < 16; o <<= 1) ss += __shfl_xor(ss, o);
            if ((lane & 15) == 0) hks[wid * 16 + (lane >> 4) * 4 + j] = -0.5f * ss;
        }
    }
    __syncthreads();

    int w = wid, l = lane;
    int fr = l & 15, fq = (l >> 4) * 8;
    short8 xb0 = *(const short8*)&Xs[w * 16 + fr][fq];
    short8 xb1 = *(const short8*)&Xs[w * 16 + fr][32 + fq];
    int n_loc = w * 16 + fr;
    float hval = (z == 1) ? hks[n_loc] : 0.f;
    __syncthreads();  // xb/hks reads done; Xs region becomes kpl

    short (*kpl2)[300] = (short(*)[300])kpl;
    const float cnorm = 0.06131393394849658f;  // 266^-0.5
#pragma unroll
    for (int tr = 0; tr < 18; ++tr) {
        int row = tr * 16 + fr;
        short8 a0 = *(const short8*)&rfb[(size_t)row * DK + fq];
        short8 a1 = *(const short8*)&rfb[(size_t)row * DK + 32 + fq];
        f32x4 facc = {0.f, 0.f, 0.f, 0.f};
        facc = __builtin_amdgcn_mfma_f32_16x16x32_bf16(a0, xb0, facc, 0, 0, 0);
        facc = __builtin_amdgcn_mfma_f32_16x16x32_bf16(a1, xb1, facc, 0, 0, 0);
        sv4 o;
        for (int j = 0; j < 4; ++j) {
            int m = tr * 16 + (l >> 4) * 4 + j;
            float val = (m < MFEAT) ? cnorm * (__expf(facc[j] + hval) + KERNEL_EPS) : 0.f;
            o[j] = f2bf(val);
        }
        *(sv4*)&kpl2[n_loc][tr * 16 + (l >> 4) * 4] = o;
    }
    __syncthreads();
    short* outp = (z == 0) ? qp : kp;
    for (int lp = 0; lp < 9; ++lp) {
        int c = tid + lp * 256;      // 64 rows * 36 chunks
        int nn = c / 36, c8 = c % 36;
        short8 v = *(const short8*)&kpl2[nn][c8 * 8];
        *(short8*)&outp[((size_t)h * NSEQ + n0 + nn) * MPAD + c8 * 8] = v;
    }
}

// ---------------- phase A (MFMA): per-chunk sums -> bf16 KVc[(h,t,dv)][m], fp32 Ks[(h,t)][m] ----------------
__global__ __launch_bounds__(256) void chunksum_kernel(const short* __restrict__ kp,
                                                       const short* __restrict__ vh,
                                                       short* __restrict__ KVc,
                                                       float* __restrict__ Ks) {
    int t = blockIdx.x, h = blockIdx.y;
    __shared__ short kpT[288 * 72];   // [m][i-swizzled], stride 72 shorts (144B); 41.5KB
    __shared__ short Vt[64][72];      // [dv][i]
    int tid = threadIdx.x;
    int w = tid >> 6, l = tid & 63;
    int fr = l & 15, fq8 = (l >> 4) * 8;
    const short* kpb = kp + ((size_t)h * NSEQ + (size_t)t * 64) * MPAD;

    for (int lp = 0; lp < 9; ++lp) {
        int c = tid + lp * 256;       // 2304 = 64 i * 36 m-chunks
        int i = c / 36, c8 = c % 36;
        short8 v = *(const short8*)&kpb[(size_t)i * MPAD + c8 * 8];
        int i8 = i >> 3, i7 = i & 7;
        for (int jj = 0; jj < 8; ++jj) {
            int m = c8 * 8 + jj;
            int ig = i8 ^ ((m >> 3) & 7);
            kpT[m * 72 + ig * 8 + i7] = v[jj];
        }
    }
    for (int lp = 0; lp < 2; ++lp) {
        int c = tid + lp * 256;       // 512 = 64 i * 8 d-chunks
        int i = c & 63, d8 = (c >> 6) * 8;
        short8 v = *(const short8*)&vh[(size_t)(t * 64 + i) * DMODEL + h * DV + d8];
        for (int jj = 0; jj < 8; ++jj) Vt[d8 + jj][i] = v[jj];
    }
    __syncthreads();

    f32x4 acc[5][4];
#pragma unroll
    for (int tt = 0; tt < 5; ++tt)
        for (int nf = 0; nf < 4; ++nf) acc[tt][nf] = f32x4{0, 0, 0, 0};
#pragma unroll
    for (int tt = 0; tt < 5; ++tt) {
        int tr = w + tt * 4;
        if (tr < 18) {
            int row = tr * 16 + fr;
            int swz = (row >> 3) & 7;
            short8 a0 = *(const short8*)&kpT[row * 72 + (((fq8 >> 3)) ^ swz) * 8];
            short8 a1 = *(const short8*)&kpT[row * 72 + ((4 + (fq8 >> 3)) ^ swz) * 8];
            for (int nf = 0; nf < 4; ++nf) {
                short8 b0 = *(const short8*)&Vt[nf * 16 + fr][fq8];
                short8 b1 = *(const short8*)&Vt[nf * 16 + fr][32 + fq8];
                acc[tt][nf] = __builtin_amdgcn_mfma_f32_16x16x32_bf16(a0, b0, acc[tt][nf], 0, 0, 0);
                acc[tt][nf] = __builtin_amdgcn_mfma_f32_16x16x32_bf16(a1, b1, acc[tt][nf], 0, 0, 0);
            }
        }
    }
    for (int m = tid; m < MPAD; m += 256) {
        int swz = (m >> 3) & 7;
        float s = 0.f;
        for (int i8 = 0; i8 < 8; ++i8) {
            int ig = i8 ^ swz;
            for (int j = 0; j < 8; ++j) s += bf2f(kpT[m * 72 + ig * 8 + j]);
        }
        Ks[((size_t)h * NT + t) * MPAD + m] = s;
    }
    __syncthreads();  // kpT reads done; overlay kvT
    short* kvT = kpT; // [64 dv][296 m]
#pragma unroll
    for (int tt = 0; tt < 5; ++tt) {
        int tr = w + tt * 4;
        if (tr < 18) {
            for (int nf = 0; nf < 4; ++nf) {
                int dv = nf * 16 + fr;
                for (int j = 0; j < 4; ++j) {
                    int m = tr * 16 + (l >> 4) * 4 + j;
                    kvT[dv * 296 + m] = f2bf(acc[tt][nf][j]);
                }
            }
        }
    }
    __syncthreads();
    for (int lp = 0; lp < 9; ++lp) {
        int c = tid + lp * 256;       // 2304 = 64 dv * 36
        int dv = c / 36, c8 = c % 36;
        short8 v = *(const short8*)&kvT[dv * 296 + c8 * 8];
        *(short8*)&KVc[(((size_t)h * NT + t) * DV + dv) * MPAD + c8 * 8] = v;
    }
}

// ---------------- fused exclusive chunk-scans, batched loads ----------------
__global__ __launch_bounds__(256) void scan_kernel(const short* __restrict__ KVc,
                                                   short* __restrict__ KVbT,
                                                   float* __restrict__ Ks,
                                                   float* __restrict__ Ktot) {
    int idx = blockIdx.x * 256 + threadIdx.x;
    const int NKV = NHEAD * DV * MPAD;       // 147456
    if (idx < NKV) {
        int h = idx / (DV * MPAD);
        int rem = idx % (DV * MPAD);
        size_t base = (size_t)h * NT * DV * MPAD + rem;
        short vals[NT];
#pragma unroll
        for (int t = 0; t < NT; ++t) vals[t] = KVc[base + (size_t)t * DV * MPAD];
        float run = 0.f;
#pragma unroll
        for (int t = 0; t < NT; ++t) {
            KVbT[base + (size_t)t * DV * MPAD] = f2bf(run);
            run += bf2f(vals[t]);
        }
    } else {
        int j = idx - NKV;
        if (j < NHEAD * MPAD) {
            int h = j / MPAD, m = j % MPAD;
            size_t base = (size_t)h * NT * MPAD + m;
            float vals[NT];
#pragma unroll
            for (int t = 0; t < NT; ++t) vals[t] = Ks[base + (size_t)t * MPAD];
            float run = 0.f;
#pragma unroll
            for (int t = 0; t < NT; ++t) {
                Ks[base + (size_t)t * MPAD] = run;
                run += vals[t];
            }
            Ktot[(size_t)h * MPAD + m] = run;
        }
    }
}

// ---------------- phase C: MFMA intra+inter+denominators; bf16 out ----------------
__global__ __launch_bounds__(256) void phasec_kernel(const short* __restrict__ qp,
                                                     const short* __restrict__ kp,
                                                     const short* __restrict__ vh,
                                                     const short* __restrict__ KVbT,
                                                     const float* __restrict__ Ks,
                                                     const float* __restrict__ Ktot,
                                                     short* __restrict__ attn) {
    int t = blockIdx.x, h = blockIdx.y;
    __shared__ short Buf[64][296];   // Kp (QK^T phase) then St (inter phase)
    __shared__ short Vt[64][72];     // [dv][i]
    __shared__ short Am[64][72];     // masked A, bf16
    __shared__ float Ksp[MPAD], Ktp[MPAD];
    __shared__ float fscale_s[64];
    int tid = threadIdx.x;
    int w = tid >> 6, l = tid & 63;
    int fr = l & 15, fq = (l >> 4) * 8;
    const short* qpb = qp + ((size_t)h * NSEQ + (size_t)t * 64) * MPAD;
    const short* kpb = kp + ((size_t)h * NSEQ + (size_t)t * 64) * MPAD;
    const short* stb = KVbT + ((size_t)h * NT + t) * DV * MPAD;

    short8 qf[9];
#pragma unroll
    for (int ks = 0; ks < 9; ++ks)
        qf[ks] = *(const short8*)&qpb[(size_t)(w * 16 + fr) * MPAD + ks * 32 + fq];

    int srow = tid >> 2, sc4 = tid & 3;
#pragma unroll
    for (int lp = 0; lp < 9; ++lp) {
        int c = sc4 + lp * 4;
        *(short8*)&Buf[srow][c * 8] = *(const short8*)&kpb[(size_t)srow * MPAD + c * 8];
    }
    for (int lp = 0; lp < 2; ++lp) {
        int c = tid + lp * 256;
        int i = c & 63, d8 = (c >> 6) * 8;
        short8 v = *(const short8*)&vh[(size_t)(t * 64 + i) * DMODEL + h * DV + d8];
        for (int jj = 0; jj < 8; ++jj) Vt[d8 + jj][i] = v[jj];
    }
    for (int idx = tid; idx < MPAD; idx += 256) {
        Ksp[idx] = Ks[((size_t)h * NT + t) * MPAD + idx];
        Ktp[idx] = Ktot[(size_t)h * MPAD + idx];
    }
    short8 stg[9];
#pragma unroll
    for (int lp = 0; lp < 9; ++lp) {
        int c = sc4 + lp * 4;
        stg[lp] = *(const short8*)&stb[(size_t)srow * MPAD + c * 8];
    }
    __syncthreads();

    f32x4 accA[4] = {f32x4{0,0,0,0}, f32x4{0,0,0,0}, f32x4{0,0,0,0}, f32x4{0,0,0,0}};
    f32x4 accO[4] = {f32x4{0,0,0,0}, f32x4{0,0,0,0}, f32x4{0,0,0,0}, f32x4{0,0,0,0}};
#pragma unroll 3
    for (int ks = 0; ks < 9; ++ks) {
        int ko = ks * 32 + fq;
        for (int nf = 0; nf < 4; ++nf) {
            short8 bk = *(const short8*)&Buf[nf * 16 + fr][ko];
            accA[nf] = __builtin_amdgcn_mfma_f32_16x16x32_bf16(qf[ks], bk, accA[nf], 0, 0, 0);
        }
    }
    __syncthreads();
#pragma unroll
    for (int lp = 0; lp < 9; ++lp) {
        int c = sc4 + lp * 4;
        *(short8*)&Buf[srow][c * 8] = stg[lp];
    }
    for (int nf = 0; nf < 4; ++nf) {
        int col = nf * 16 + fr;
        for (int j = 0; j < 4; ++j) {
            int row = w * 16 + (l >> 4) * 4 + j;
            Am[row][col] = (col <= row) ? f2bf(accA[nf][j]) : (short)0;
        }
    }
    __syncthreads();
#pragma unroll 3
    for (int ks = 0; ks < 9; ++ks) {
        int ko = ks * 32 + fq;
        for (int nf = 0; nf < 4; ++nf) {
            short8 bs = *(const short8*)&Buf[nf * 16 + fr][ko];
            accO[nf] = __builtin_amdgcn_mfma_f32_16x16x32_bf16(qf[ks], bs, accO[nf], 0, 0, 0);
        }
    }
#pragma unroll
    for (int ks = 0; ks < 2; ++ks) {
        int ko = ks * 32 + fq;
        short8 a = *(const short8*)&Am[w * 16 + fr][ko];
        for (int nf = 0; nf < 4; ++nf) {
            short8 b = *(const short8*)&Vt[nf * 16 + fr][ko];
            accO[nf] = __builtin_amdgcn_mfma_f32_16x16x32_bf16(a, b, accO[nf], 0, 0, 0);
        }
    }
    int di = tid >> 2, dp = tid & 3;
    float dc = 0.f, df = 0.f;
    {
        const short* amrow = &Am[di][dp * 16];
        short8 s0 = *(const short8*)amrow;
        short8 s1 = *(const short8*)(amrow + 8);
        for (int j2 = 0; j2 < 8; ++j2) dc += bf2f(s0[j2]) + bf2f(s1[j2]);
    }
#pragma unroll
    for (int c8 = 0; c8 < 9; ++c8) {
        int m = dp * 72 + c8 * 8;
        short8 qv = *(const short8*)&qpb[(size_t)di * MPAD + m];
        for (int j2 = 0; j2 < 8; ++j2) {
            float qq = bf2f(qv[j2]);
            dc += qq * Ksp[m + j2];
            df += qq * Ktp[m + j2];
        }
    }
    dc += __shfl_xor(dc, 1); dc += __shfl_xor(dc, 2);
    df += __shfl_xor(df, 1); df += __shfl_xor(df, 2);
    if (dp == 0) {
        float dst = df;
        if (fabsf(dst) <= NORM_STAB) dst += 2.f * NORM_STAB;
        fscale_s[di] = (1.f / dc) / dst;
    }
    __syncthreads();
    for (int nf = 0; nf < 4; ++nf) {
        int col = nf * 16 + fr;
        for (int j = 0; j < 4; ++j) {
            int row = w * 16 + (l >> 4) * 4 + j;
            attn[((size_t)t * 64 + row) * DMODEL + h * DV + col] =
                f2bf(accO[nf][j] * fscale_s[row]);
        }
    }
}

// ---------------- final GEMM with bias + residual (A bf16, B pre-transposed bf16; pipelined) ----------------
__global__ __launch_bounds__(256) void fgemm_kernel(const short* __restrict__ A,
                                                    const short* __restrict__ Bt,
                                                    float* __restrict__ C,
                                                    const float* __restrict__ bias,
                                                    const float* __restrict__ residual) {
    __shared__ short AsB[128][40];
    __shared__ short BsB[128][40];
    int bm = blockIdx.y * 64, bn = blockIdx.x * 64;
    int tid = threadIdx.x;
    int wid = tid >> 6, lane = tid & 63;
    f32x4 acc[4] = {f32x4{0,0,0,0}, f32x4{0,0,0,0}, f32x4{0,0,0,0}, f32x4{0,0,0,0}};
    int ar = tid >> 2, akq = tid & 3;
    short8 aReg = *(const short8*)&A[(size_t)(bm + ar) * DMODEL + akq * 8];
    short8 bReg = *(const short8*)&Bt[(size_t)(bn + ar) * DMODEL + akq * 8];
    int buf = 0;
#pragma unroll 2
    for (int k0 = 0; k0 < DMODEL; k0 += 32) {
        *(short8*)&AsB[buf * 64 + ar][akq * 8] = aReg;
        *(short8*)&BsB[buf * 64 + ar][akq * 8] = bReg;
        __syncthreads();
        if (k0 + 32 < DMODEL) {
            aReg = *(const short8*)&A[(size_t)(bm + ar) * DMODEL + k0 + 32 + akq * 8];
            bReg = *(const short8*)&Bt[(size_t)(bn + ar) * DMODEL + k0 + 32 + akq * 8];
        }
        int row = buf * 64 + wid * 16 + (lane & 15);
        int koff = (lane >> 4) * 8;
        short8 a = *(const short8*)&AsB[row][koff];
        for (int nf = 0; nf < 4; ++nf) {
            int col = buf * 64 + nf * 16 + (lane & 15);
            short8 b = *(const short8*)&BsB[col][koff];
            acc[nf] = __builtin_amdgcn_mfma_f32_16x16x32_bf16(a, b, acc[nf], 0, 0, 0);
        }
        buf ^= 1;
    }
    for (int nf = 0; nf < 4; ++nf) {
        int col = bn + nf * 16 + (lane & 15);
        for (int j = 0; j < 4; ++j) {
            int row = bm + wid * 16 + (lane >> 4) * 4 + j;
            C[(size_t)row * DMODEL + col] =
                acc[nf][j] + bias[col] + residual[(size_t)row * DMODEL + col];
        }
    }
}

extern "C" void kernel_launch(void* const* d_in, const int* in_sizes, int n_in,
                              void* d_out, int out_size, void* d_ws, size_t ws_size,
                              hipStream_t stream) {
    const float* q = (const float*)d_in[0];
    const float* k = (const float*)d_in[1];
    const float* v = (const float*)d_in[2];
    const float* Wq = (const float*)d_in[3];
    const float* Wk = (const float*)d_in[4];
    const float* Wv = (const float*)d_in[5];
    const float* Wfc = (const float*)d_in[6];
    const float* bfc = (const float*)d_in[7];
    const float* gamma = (const float*)d_in[8];
    const float* beta = (const float*)d_in[9];
    const float* rf = (const float*)d_in[10];
    float* out = (float*)d_out;

    float* ws = (float*)d_ws;
    short* attn = (short*)ws;                              // bf16 2048*512
    short* vhb = attn + (size_t)NSEQ * DMODEL;             // bf16 2048*512
    short* qp = vhb + (size_t)NSEQ * DMODEL;               // bf16 8*2048*288
    short* kp = qp + (size_t)NHEAD * NSEQ * MPAD;
    short* KVc = kp + (size_t)NHEAD * NSEQ * MPAD;         // bf16 8*32*64*288
    short* KVbT = KVc + (size_t)NHEAD * NT * DV * MPAD;
    float* Ks = (float*)(KVbT + (size_t)NHEAD * NT * DV * MPAD);   // fp32 8*32*288
    float* Ktot = Ks + (size_t)NHEAD * NT * MPAD;          // 8*288
    short* Wqt = (short*)(Ktot + (size_t)NHEAD * MPAD);    // bf16 512*512 each
    short* Wkt = Wqt + (size_t)DMODEL * DMODEL;
    short* Wvt = Wkt + (size_t)DMODEL * DMODEL;
    short* Wfct = Wvt + (size_t)DMODEL * DMODEL;
    short* rfb = Wfct + (size_t)DMODEL * DMODEL;           // bf16 288*64

    dim3 gp(8, 8, 5);
    prep_kernel<<<gp, 256, 0, stream>>>(Wq, Wk, Wv, Wfc, rf, Wqt, Wkt, Wvt, Wfct, rfb);
    dim3 gq(NT, NHEAD, 3);
    qkvfeat_kernel<<<gq, 256, 0, stream>>>(q, k, v, Wqt, Wkt, Wvt, gamma, beta, rfb,
                                           vhb, qp, kp);
    dim3 ga(NT, NHEAD);
    chunksum_kernel<<<ga, 256, 0, stream>>>(kp, vhb, KVc, Ks);
    int scan_threads = NHEAD * DV * MPAD + NHEAD * MPAD;
    scan_kernel<<<(scan_threads + 255) / 256, 256, 0, stream>>>(KVc, KVbT, Ks, Ktot);
    dim3 gc(NT, NHEAD);
    phasec_kernel<<<gc, 256, 0, stream>>>(qp, kp, vhb, KVbT, Ks, Ktot, attn);
    dim3 g(DMODEL / 64, NSEQ / 64);
    fgemm_kernel<<<g, 256, 0, stream>>>(attn, Wfct, out, bfc, q);
}